// Round 9
// baseline (427.733 us; speedup 1.0000x reference)
//
#include <hip/hip_runtime.h>

#define NCOL 64
#define NXCD 8

// ---------------- bf16 helpers (RNE pack, bit-shift unpack) ----------------

__device__ __forceinline__ unsigned int bf16pair(float a, float b) {
  unsigned int ua = __float_as_uint(a), ub = __float_as_uint(b);
  ua = (ua + 0x7FFFu + ((ua >> 16) & 1u)) >> 16;
  ub = (ub + 0x7FFFu + ((ub >> 16) & 1u)) >> 16;
  return (ub << 16) | ua;
}
__device__ __forceinline__ float bf_lo(unsigned int v) { return __uint_as_float(v << 16); }
__device__ __forceinline__ float bf_hi(unsigned int v) { return __uint_as_float(v & 0xFFFF0000u); }

// ---------------- degree (XCD-partitioned by dst range) ----------------

__global__ void deg_part(const int* __restrict__ dst, int* __restrict__ degi,
                         int ne, int n) {
  int chunk = (n + NXCD - 1) / NXCD;
  int g = blockIdx.x & (NXCD - 1);
  int lo = g * chunk, hi = min(lo + chunk, n);
  int tid = (blockIdx.x >> 3) * blockDim.x + threadIdx.x;
  int stride = (gridDim.x >> 3) * blockDim.x;
  for (int i = tid; i < ne; i += stride) {
    int d = dst[i];
    if (d >= lo && d < hi) atomicAdd(&degi[d], 1);
  }
}

__global__ void dinv_kernel(const int* __restrict__ degi, float* __restrict__ dinv, int n) {
  int i = blockIdx.x * blockDim.x + threadIdx.x;
  if (i < n) dinv[i] = rsqrtf((float)degi[i] + 1.0f);
}

// ---------------- graph-run boundaries (batch is SORTED -> no atomics) ----------------

__global__ void bounds_kernel(const int* __restrict__ batch, int* __restrict__ startg,
                              int* __restrict__ endg, int n) {
  int i = blockIdx.x * blockDim.x + threadIdx.x;
  if (i >= n) return;
  int b = batch[i];
  if (i == 0) {
    startg[b] = 0;
  } else {
    int bp = batch[i - 1];
    if (b != bp) { startg[b] = i; endg[bp] = i; }
  }
  if (i == n - 1) endg[b] = n;
}

// ---------------- 3-pass exclusive scan of degrees -> rowptr[0..n] + cursor ----------------

#define SCAN_C 8

__global__ void scan_part(const int* __restrict__ degi, int* __restrict__ tsum,
                          int n, int nthreads) {
  int t = blockIdx.x * blockDim.x + threadIdx.x;
  if (t >= nthreads) return;
  int lo = t * SCAN_C, hi = min(lo + SCAN_C, n);
  int s = 0;
  for (int i = lo; i < hi; ++i) s += degi[i];
  tsum[t] = s;
}

__global__ void scan_mid(int* __restrict__ tsum, int* __restrict__ toff, int nthreads) {
  __shared__ int part[1024];
  int t = threadIdx.x;
  int chunk = (nthreads + 1023) >> 10;
  int lo = t * chunk, hi = min(lo + chunk, nthreads);
  int s = 0;
  for (int i = lo; i < hi; ++i) s += tsum[i];
  part[t] = s;
  __syncthreads();
  for (int d = 1; d < 1024; d <<= 1) {
    int v = (t >= d) ? part[t - d] : 0;
    __syncthreads();
    part[t] += v;
    __syncthreads();
  }
  int off = part[t] - s;
  for (int i = lo; i < hi; ++i) { toff[i] = off; off += tsum[i]; }
}

__global__ void scan_fill(const int* __restrict__ degi, const int* __restrict__ toff,
                          int* __restrict__ rowptr, int* __restrict__ cursor,
                          int n, int nthreads) {
  int t = blockIdx.x * blockDim.x + threadIdx.x;
  if (t >= nthreads) return;
  int lo = t * SCAN_C, hi = min(lo + SCAN_C, n);
  int off = toff[t];
  for (int i = lo; i < hi; ++i) {
    rowptr[i] = off;
    cursor[i] = off;
    off += degi[i];
  }
  if (hi == n) rowptr[n] = off;
}

// ---------------- CSR fill (XCD-partitioned; atomicExch store -> L2-allocated lines) ----------------

__global__ void csr_fill_part(const int* __restrict__ src, const int* __restrict__ dst,
                              int* __restrict__ cursor, int* __restrict__ csr_src,
                              int ne, int n) {
  int chunk = (n + NXCD - 1) / NXCD;
  int g = blockIdx.x & (NXCD - 1);
  int lo = g * chunk, hi = min(lo + chunk, n);
  int tid = (blockIdx.x >> 3) * blockDim.x + threadIdx.x;
  int stride = (gridDim.x >> 3) * blockDim.x;
  for (int i = tid; i < ne; i += stride) {
    int d = dst[i];
    if (d >= lo && d < hi) {
      int pos = atomicAdd(&cursor[d], 1);
      // plain 4B store would be a partial-line HBM write (L2 no-write-allocate);
      // atomicExch executes in L2 and allocates the line -> ~16 entries/line merge.
      atomicExch(&csr_src[pos], src[i]);
    }
  }
}

// ---------------- tiled tall-skinny GEMM -> bf16 messages ----------------
// Block = 256 threads = 4 waves, owns 64 rows. X tile staged in LDS
// ([64][K+1] pad). Wave w owns 16 cols; W address wave-uniform -> s_load.

template<int K>
__global__ __launch_bounds__(256, 4) void gemm_tiled(
    const float* __restrict__ X, const float* __restrict__ W,
    const float* __restrict__ dinv, unsigned int* __restrict__ Ybf, int n) {
  __shared__ float XS[64][K + 1];
  int tid = threadIdx.x;
  int rows0 = blockIdx.x * 64;

  const int K4 = K / 4;
  for (int f = tid; f < 64 * K4; f += 256) {
    int r = f / K4, k4 = (f % K4) * 4;
    int gr = min(rows0 + r, n - 1);
    float4 v = *reinterpret_cast<const float4*>(X + (size_t)gr * K + k4);
    XS[r][k4 + 0] = v.x; XS[r][k4 + 1] = v.y;
    XS[r][k4 + 2] = v.z; XS[r][k4 + 3] = v.w;
  }
  __syncthreads();

  int lane = tid & 63;
  int cgrp = __builtin_amdgcn_readfirstlane(tid >> 6);
  int gr = rows0 + lane;

  float acc[16];
#pragma unroll
  for (int c = 0; c < 16; ++c) acc[c] = 0.f;

  const float* wbase = W + cgrp * 16;
#pragma unroll 4
  for (int k = 0; k < K; ++k) {
    float xk = XS[lane][k];
    const float* wr = wbase + (size_t)k * NCOL;
#pragma unroll
    for (int c = 0; c < 16; c += 4) {
      float4 wv = *reinterpret_cast<const float4*>(wr + c);
      acc[c + 0] = fmaf(xk, wv.x, acc[c + 0]);
      acc[c + 1] = fmaf(xk, wv.y, acc[c + 1]);
      acc[c + 2] = fmaf(xk, wv.z, acc[c + 2]);
      acc[c + 3] = fmaf(xk, wv.w, acc[c + 3]);
    }
  }

  if (gr < n) {
    float d = dinv[gr];
    unsigned int* yr = Ybf + (size_t)gr * (NCOL / 2) + cgrp * 8;
    uint4 o0, o1;
    o0.x = bf16pair(acc[0] * d,  acc[1] * d);
    o0.y = bf16pair(acc[2] * d,  acc[3] * d);
    o0.z = bf16pair(acc[4] * d,  acc[5] * d);
    o0.w = bf16pair(acc[6] * d,  acc[7] * d);
    o1.x = bf16pair(acc[8] * d,  acc[9] * d);
    o1.y = bf16pair(acc[10] * d, acc[11] * d);
    o1.z = bf16pair(acc[12] * d, acc[13] * d);
    o1.w = bf16pair(acc[14] * d, acc[15] * d);
    *reinterpret_cast<uint4*>(yr) = o0;
    *reinterpret_cast<uint4*>(yr + 4) = o1;
  }
}

// ---------------- CSR gather-aggregate over bf16 messages ----------------

template<bool RELU>
__global__ void aggregate(const int* __restrict__ rowptr, const int* __restrict__ csr_src,
                          const unsigned int* __restrict__ Ybf, const float* __restrict__ dinv,
                          const float* __restrict__ bias, float* __restrict__ H, int n) {
  int nd = (blockIdx.x * blockDim.x + threadIdx.x) >> 6;
  if (nd >= n) return;
  nd = __builtin_amdgcn_readfirstlane(nd);
  int lane = threadIdx.x & 63;
  int c2 = lane & 31;
  int half = lane >> 5;
  int lo = rowptr[nd], hi = rowptr[nd + 1];
  float ax = 0.f, ay = 0.f;
  if (half == 0) {
    unsigned int v = Ybf[(size_t)nd * 32 + c2];
    ax = bf_lo(v); ay = bf_hi(v);
  }
  int p = lo + half;
  for (; p + 6 < hi; p += 8) {
    int s0 = csr_src[p],     s1 = csr_src[p + 2];
    int s2 = csr_src[p + 4], s3 = csr_src[p + 6];
    unsigned int v0 = Ybf[(size_t)s0 * 32 + c2];
    unsigned int v1 = Ybf[(size_t)s1 * 32 + c2];
    unsigned int v2 = Ybf[(size_t)s2 * 32 + c2];
    unsigned int v3 = Ybf[(size_t)s3 * 32 + c2];
    ax += bf_lo(v0); ay += bf_hi(v0);
    ax += bf_lo(v1); ay += bf_hi(v1);
    ax += bf_lo(v2); ay += bf_hi(v2);
    ax += bf_lo(v3); ay += bf_hi(v3);
  }
  for (; p < hi; p += 2) {
    unsigned int v = Ybf[(size_t)csr_src[p] * 32 + c2];
    ax += bf_lo(v); ay += bf_hi(v);
  }
  ax += __shfl_xor(ax, 32);
  ay += __shfl_xor(ay, 32);
  if (half == 0) {
    float d = dinv[nd];
    float vx = fmaf(d, ax, bias[2 * c2]);
    float vy = fmaf(d, ay, bias[2 * c2 + 1]);
    if (RELU) { vx = fmaxf(vx, 0.f); vy = fmaxf(vy, 0.f); }
    reinterpret_cast<float2*>(H)[(size_t)nd * 32 + c2] = make_float2(vx, vy);
  }
}

// ---------------- pooling: pool[g,:] += H over sorted batch runs ----------------

#define NPG 64

__global__ void pool_kernel(const float* __restrict__ H, const int* __restrict__ batch,
                            float* __restrict__ pool, int n) {
  int gid = (blockIdx.x * blockDim.x + threadIdx.x) >> 6;
  int c = threadIdx.x & 63;
  int n0 = gid * NPG;
  if (n0 >= n) return;
  int n1 = min(n0 + NPG, n);
  float acc = 0.f;
  int curg = batch[n0];
  for (int nd = n0; nd < n1; ++nd) {
    int g = batch[nd];
    if (g != curg) {
      atomicAdd(&pool[(size_t)curg * NCOL + c], acc);
      acc = 0.f;
      curg = g;
    }
    acc += H[(size_t)nd * NCOL + c];
  }
  atomicAdd(&pool[(size_t)curg * NCOL + c], acc);
}

// ---------------- final tiny GEMM: out = (pool/cnt) @ Wl + bl ----------------

__global__ void final_kernel(const float* __restrict__ pool, const int* __restrict__ startg,
                             const int* __restrict__ endg, const float* __restrict__ Wl,
                             const float* __restrict__ bl, float* __restrict__ out, int ng) {
  int t = threadIdx.x;
  if (t >= ng * 6) return;
  int g = t / 6, o = t % 6;
  float cntf = (float)(endg[g] - startg[g]);
  float inv = 1.0f / fmaxf(cntf, 1.0f);
  float s = 0.f;
#pragma unroll
  for (int c = 0; c < NCOL; ++c) s += pool[(size_t)g * NCOL + c] * Wl[c * 6 + o];
  out[t] = fmaf(s, inv, bl[o]);
}

// ---------------- launch ----------------

extern "C" void kernel_launch(void* const* d_in, const int* in_sizes, int n_in,
                              void* d_out, int out_size, void* d_ws, size_t ws_size,
                              hipStream_t stream) {
  const float* x    = (const float*)d_in[0];
  const int*   ei   = (const int*)d_in[1];
  const int*   batch= (const int*)d_in[2];
  const float* W1   = (const float*)d_in[3];
  const float* b1   = (const float*)d_in[4];
  const float* W2   = (const float*)d_in[5];
  const float* b2   = (const float*)d_in[6];
  const float* Wl   = (const float*)d_in[7];
  const float* bl   = (const float*)d_in[8];
  float* out = (float*)d_out;

  int n  = in_sizes[0] / 128;   // 100000
  int ne = in_sizes[1] / 2;     // 1600000
  int ng = out_size / 6;        // 64
  const int* srcI = ei;
  const int* dstI = ei + ne;

  char* w = (char*)d_ws;
  size_t o = 0;
  auto take = [&](size_t bytes) -> char* {
    char* p = w + o;
    o = (o + bytes + 255) & ~(size_t)255;
    return p;
  };
  float*        dinv    = (float*)take((size_t)n * 4);
  int*          degi    = (int*)  take((size_t)n * 4);
  int*          cursor  = (int*)  take((size_t)n * 4);
  int*          rowptr  = (int*)  take((size_t)(n + 1) * 4);
  int*          csr_src = (int*)  take((size_t)ne * 4);
  unsigned int* Ybf     = (unsigned int*)take((size_t)n * (NCOL / 2) * 4);
  float*        H       = (float*)take((size_t)n * NCOL * 4);
  float*        pool    = (float*)take(4096 * 4);
  int*          startg  = (int*)  take(64 * 4);
  int*          endg    = (int*)  take(64 * 4);
  int*          tsum    = (int*)  take(16384 * 4);
  int*          toff    = (int*)  take(16384 * 4);

  hipMemsetAsync(degi, 0, (size_t)n * 4, stream);
  hipMemsetAsync(pool, 0, 4096 * 4, stream);
  hipMemsetAsync(startg, 0, 64 * 4, stream);
  hipMemsetAsync(endg, 0, 64 * 4, stream);

  int nb256 = (n + 255) / 256;
  int nthreads = (n + SCAN_C - 1) / SCAN_C;
  int nbScan = (nthreads + 255) / 256;

  // CSR build (shared by both layers); XCD-partitioned atomics/writes
  deg_part<<<1024, 256, 0, stream>>>(dstI, degi, ne, n);
  bounds_kernel<<<nb256, 256, 0, stream>>>(batch, startg, endg, n);
  dinv_kernel<<<nb256, 256, 0, stream>>>(degi, dinv, n);
  scan_part<<<nbScan, 256, 0, stream>>>(degi, tsum, n, nthreads);
  scan_mid<<<1, 1024, 0, stream>>>(tsum, toff, nthreads);
  scan_fill<<<nbScan, 256, 0, stream>>>(degi, toff, rowptr, cursor, n, nthreads);
  csr_fill_part<<<1024, 256, 0, stream>>>(srcI, dstI, cursor, csr_src, ne, n);

  int nbAgg = (n * 64 + 255) / 256;
  int nbGemm = (n + 63) / 64;

  // layer 1: Ybf = bf16((x@W1)*dinv) ; H = relu(dinv*(Y_self + sum Y[src]) + b1)
  gemm_tiled<128><<<nbGemm, 256, 0, stream>>>(x, W1, dinv, Ybf, n);
  aggregate<true><<<nbAgg, 256, 0, stream>>>(rowptr, csr_src, Ybf, dinv, b1, H, n);

  // layer 2: Ybf = bf16((H@W2)*dinv) ; H = dinv*(Y_self + sum Y[src]) + b2
  gemm_tiled<64><<<nbGemm, 256, 0, stream>>>(H, W2, dinv, Ybf, n);
  aggregate<false><<<nbAgg, 256, 0, stream>>>(rowptr, csr_src, Ybf, dinv, b2, H, n);

  // pool + head
  int ngroups = (n + NPG - 1) / NPG;
  int pblocks = (ngroups * 64 + 255) / 256;
  pool_kernel<<<pblocks, 256, 0, stream>>>(H, batch, pool, n);
  final_kernel<<<1, 384, 0, stream>>>(pool, startg, endg, Wl, bl, out, ng);
}

// Round 10
// 423.378 us; speedup vs baseline: 1.0103x; 1.0103x over previous
//
#include <hip/hip_runtime.h>

#define NCOL 64
#define NXCD 8

// ---------------- bf16 helpers (RNE pack, bit-shift unpack) ----------------

__device__ __forceinline__ unsigned int bf16pair(float a, float b) {
  unsigned int ua = __float_as_uint(a), ub = __float_as_uint(b);
  ua = (ua + 0x7FFFu + ((ua >> 16) & 1u)) >> 16;
  ub = (ub + 0x7FFFu + ((ub >> 16) & 1u)) >> 16;
  return (ub << 16) | ua;
}
__device__ __forceinline__ float bf_lo(unsigned int v) { return __uint_as_float(v << 16); }
__device__ __forceinline__ float bf_hi(unsigned int v) { return __uint_as_float(v & 0xFFFF0000u); }

// ---------------- degree (XCD-partitioned; nt streaming reads) ----------------

__global__ void deg_part(const int* __restrict__ dst, int* __restrict__ degi,
                         int ne, int n) {
  int chunk = (n + NXCD - 1) / NXCD;
  int g = blockIdx.x & (NXCD - 1);
  int lo = g * chunk, hi = min(lo + chunk, n);
  int tid = (blockIdx.x >> 3) * blockDim.x + threadIdx.x;
  int stride = (gridDim.x >> 3) * blockDim.x;
  for (int i = tid; i < ne; i += stride) {
    int d = __builtin_nontemporal_load(&dst[i]);
    if (d >= lo && d < hi) atomicAdd(&degi[d], 1);
  }
}

__global__ void dinv_kernel(const int* __restrict__ degi, float* __restrict__ dinv, int n) {
  int i = blockIdx.x * blockDim.x + threadIdx.x;
  if (i < n) dinv[i] = rsqrtf((float)degi[i] + 1.0f);
}

// ---------------- graph-run boundaries (batch is SORTED -> no atomics) ----------------

__global__ void bounds_kernel(const int* __restrict__ batch, int* __restrict__ startg,
                              int* __restrict__ endg, int n) {
  int i = blockIdx.x * blockDim.x + threadIdx.x;
  if (i >= n) return;
  int b = batch[i];
  if (i == 0) {
    startg[b] = 0;
  } else {
    int bp = batch[i - 1];
    if (b != bp) { startg[b] = i; endg[bp] = i; }
  }
  if (i == n - 1) endg[b] = n;
}

// ---------------- 3-pass exclusive scan of degrees -> rowptr[0..n] + cursor ----------------

#define SCAN_C 8

__global__ void scan_part(const int* __restrict__ degi, int* __restrict__ tsum,
                          int n, int nthreads) {
  int t = blockIdx.x * blockDim.x + threadIdx.x;
  if (t >= nthreads) return;
  int lo = t * SCAN_C, hi = min(lo + SCAN_C, n);
  int s = 0;
  for (int i = lo; i < hi; ++i) s += degi[i];
  tsum[t] = s;
}

__global__ void scan_mid(int* __restrict__ tsum, int* __restrict__ toff, int nthreads) {
  __shared__ int part[1024];
  int t = threadIdx.x;
  int chunk = (nthreads + 1023) >> 10;
  int lo = t * chunk, hi = min(lo + chunk, nthreads);
  int s = 0;
  for (int i = lo; i < hi; ++i) s += tsum[i];
  part[t] = s;
  __syncthreads();
  for (int d = 1; d < 1024; d <<= 1) {
    int v = (t >= d) ? part[t - d] : 0;
    __syncthreads();
    part[t] += v;
    __syncthreads();
  }
  int off = part[t] - s;
  for (int i = lo; i < hi; ++i) { toff[i] = off; off += tsum[i]; }
}

__global__ void scan_fill(const int* __restrict__ degi, const int* __restrict__ toff,
                          int* __restrict__ rowptr, int* __restrict__ cursor,
                          int n, int nthreads) {
  int t = blockIdx.x * blockDim.x + threadIdx.x;
  if (t >= nthreads) return;
  int lo = t * SCAN_C, hi = min(lo + SCAN_C, n);
  int off = toff[t];
  for (int i = lo; i < hi; ++i) {
    rowptr[i] = off;
    cursor[i] = off;
    off += degi[i];
  }
  if (hi == n) rowptr[n] = off;
}

// ---------------- CSR fill ----------------
// XCD-partitioned. atomicExch allocates the csr line DIRTY in this XCD's L2;
// nt loads keep the streaming dst/src out of the working set so the dirty
// window (800 KB csr + 50 KB cursor) survives until all ~16 entries merge.

__global__ void csr_fill_part(const int* __restrict__ src, const int* __restrict__ dst,
                              int* __restrict__ cursor, int* __restrict__ csr_src,
                              int ne, int n) {
  int chunk = (n + NXCD - 1) / NXCD;
  int g = blockIdx.x & (NXCD - 1);
  int lo = g * chunk, hi = min(lo + chunk, n);
  int tid = (blockIdx.x >> 3) * blockDim.x + threadIdx.x;
  int stride = (gridDim.x >> 3) * blockDim.x;
  for (int i = tid; i < ne; i += stride) {
    int d = __builtin_nontemporal_load(&dst[i]);
    if (d >= lo && d < hi) {
      int s = __builtin_nontemporal_load(&src[i]);
      int pos = atomicAdd(&cursor[d], 1);
      atomicExch(&csr_src[pos], s);
    }
  }
}

// ---------------- tiled tall-skinny GEMM -> bf16 messages ----------------

template<int K>
__global__ __launch_bounds__(256, 4) void gemm_tiled(
    const float* __restrict__ X, const float* __restrict__ W,
    const float* __restrict__ dinv, unsigned int* __restrict__ Ybf, int n) {
  __shared__ float XS[64][K + 1];
  int tid = threadIdx.x;
  int rows0 = blockIdx.x * 64;

  const int K4 = K / 4;
  for (int f = tid; f < 64 * K4; f += 256) {
    int r = f / K4, k4 = (f % K4) * 4;
    int gr = min(rows0 + r, n - 1);
    float4 v = *reinterpret_cast<const float4*>(X + (size_t)gr * K + k4);
    XS[r][k4 + 0] = v.x; XS[r][k4 + 1] = v.y;
    XS[r][k4 + 2] = v.z; XS[r][k4 + 3] = v.w;
  }
  __syncthreads();

  int lane = tid & 63;
  int cgrp = __builtin_amdgcn_readfirstlane(tid >> 6);
  int gr = rows0 + lane;

  float acc[16];
#pragma unroll
  for (int c = 0; c < 16; ++c) acc[c] = 0.f;

  const float* wbase = W + cgrp * 16;
#pragma unroll 4
  for (int k = 0; k < K; ++k) {
    float xk = XS[lane][k];
    const float* wr = wbase + (size_t)k * NCOL;
#pragma unroll
    for (int c = 0; c < 16; c += 4) {
      float4 wv = *reinterpret_cast<const float4*>(wr + c);
      acc[c + 0] = fmaf(xk, wv.x, acc[c + 0]);
      acc[c + 1] = fmaf(xk, wv.y, acc[c + 1]);
      acc[c + 2] = fmaf(xk, wv.z, acc[c + 2]);
      acc[c + 3] = fmaf(xk, wv.w, acc[c + 3]);
    }
  }

  if (gr < n) {
    float d = dinv[gr];
    unsigned int* yr = Ybf + (size_t)gr * (NCOL / 2) + cgrp * 8;
    uint4 o0, o1;
    o0.x = bf16pair(acc[0] * d,  acc[1] * d);
    o0.y = bf16pair(acc[2] * d,  acc[3] * d);
    o0.z = bf16pair(acc[4] * d,  acc[5] * d);
    o0.w = bf16pair(acc[6] * d,  acc[7] * d);
    o1.x = bf16pair(acc[8] * d,  acc[9] * d);
    o1.y = bf16pair(acc[10] * d, acc[11] * d);
    o1.z = bf16pair(acc[12] * d, acc[13] * d);
    o1.w = bf16pair(acc[14] * d, acc[15] * d);
    *reinterpret_cast<uint4*>(yr) = o0;
    *reinterpret_cast<uint4*>(yr + 4) = o1;
  }
}

// ---------------- CSR gather-aggregate over bf16 messages ----------------

template<bool RELU>
__global__ void aggregate(const int* __restrict__ rowptr, const int* __restrict__ csr_src,
                          const unsigned int* __restrict__ Ybf, const float* __restrict__ dinv,
                          const float* __restrict__ bias, float* __restrict__ H, int n) {
  int nd = (blockIdx.x * blockDim.x + threadIdx.x) >> 6;
  if (nd >= n) return;
  nd = __builtin_amdgcn_readfirstlane(nd);
  int lane = threadIdx.x & 63;
  int c2 = lane & 31;
  int half = lane >> 5;
  int lo = rowptr[nd], hi = rowptr[nd + 1];
  float ax = 0.f, ay = 0.f;
  if (half == 0) {
    unsigned int v = Ybf[(size_t)nd * 32 + c2];
    ax = bf_lo(v); ay = bf_hi(v);
  }
  int p = lo + half;
  for (; p + 6 < hi; p += 8) {
    int s0 = csr_src[p],     s1 = csr_src[p + 2];
    int s2 = csr_src[p + 4], s3 = csr_src[p + 6];
    unsigned int v0 = Ybf[(size_t)s0 * 32 + c2];
    unsigned int v1 = Ybf[(size_t)s1 * 32 + c2];
    unsigned int v2 = Ybf[(size_t)s2 * 32 + c2];
    unsigned int v3 = Ybf[(size_t)s3 * 32 + c2];
    ax += bf_lo(v0); ay += bf_hi(v0);
    ax += bf_lo(v1); ay += bf_hi(v1);
    ax += bf_lo(v2); ay += bf_hi(v2);
    ax += bf_lo(v3); ay += bf_hi(v3);
  }
  for (; p < hi; p += 2) {
    unsigned int v = Ybf[(size_t)csr_src[p] * 32 + c2];
    ax += bf_lo(v); ay += bf_hi(v);
  }
  ax += __shfl_xor(ax, 32);
  ay += __shfl_xor(ay, 32);
  if (half == 0) {
    float d = dinv[nd];
    float vx = fmaf(d, ax, bias[2 * c2]);
    float vy = fmaf(d, ay, bias[2 * c2 + 1]);
    if (RELU) { vx = fmaxf(vx, 0.f); vy = fmaxf(vy, 0.f); }
    reinterpret_cast<float2*>(H)[(size_t)nd * 32 + c2] = make_float2(vx, vy);
  }
}

// ---------------- pooling: pool[g,:] += H over sorted batch runs ----------------

#define NPG 64

__global__ void pool_kernel(const float* __restrict__ H, const int* __restrict__ batch,
                            float* __restrict__ pool, int n) {
  int gid = (blockIdx.x * blockDim.x + threadIdx.x) >> 6;
  int c = threadIdx.x & 63;
  int n0 = gid * NPG;
  if (n0 >= n) return;
  int n1 = min(n0 + NPG, n);
  float acc = 0.f;
  int curg = batch[n0];
  for (int nd = n0; nd < n1; ++nd) {
    int g = batch[nd];
    if (g != curg) {
      atomicAdd(&pool[(size_t)curg * NCOL + c], acc);
      acc = 0.f;
      curg = g;
    }
    acc += H[(size_t)nd * NCOL + c];
  }
  atomicAdd(&pool[(size_t)curg * NCOL + c], acc);
}

// ---------------- final tiny GEMM: out = (pool/cnt) @ Wl + bl ----------------

__global__ void final_kernel(const float* __restrict__ pool, const int* __restrict__ startg,
                             const int* __restrict__ endg, const float* __restrict__ Wl,
                             const float* __restrict__ bl, float* __restrict__ out, int ng) {
  int t = threadIdx.x;
  if (t >= ng * 6) return;
  int g = t / 6, o = t % 6;
  float cntf = (float)(endg[g] - startg[g]);
  float inv = 1.0f / fmaxf(cntf, 1.0f);
  float s = 0.f;
#pragma unroll
  for (int c = 0; c < NCOL; ++c) s += pool[(size_t)g * NCOL + c] * Wl[c * 6 + o];
  out[t] = fmaf(s, inv, bl[o]);
}

// ---------------- launch ----------------

extern "C" void kernel_launch(void* const* d_in, const int* in_sizes, int n_in,
                              void* d_out, int out_size, void* d_ws, size_t ws_size,
                              hipStream_t stream) {
  const float* x    = (const float*)d_in[0];
  const int*   ei   = (const int*)d_in[1];
  const int*   batch= (const int*)d_in[2];
  const float* W1   = (const float*)d_in[3];
  const float* b1   = (const float*)d_in[4];
  const float* W2   = (const float*)d_in[5];
  const float* b2   = (const float*)d_in[6];
  const float* Wl   = (const float*)d_in[7];
  const float* bl   = (const float*)d_in[8];
  float* out = (float*)d_out;

  int n  = in_sizes[0] / 128;   // 100000
  int ne = in_sizes[1] / 2;     // 1600000
  int ng = out_size / 6;        // 64
  const int* srcI = ei;
  const int* dstI = ei + ne;

  char* w = (char*)d_ws;
  size_t o = 0;
  auto take = [&](size_t bytes) -> char* {
    char* p = w + o;
    o = (o + bytes + 255) & ~(size_t)255;
    return p;
  };
  float*        dinv    = (float*)take((size_t)n * 4);
  int*          degi    = (int*)  take((size_t)n * 4);
  int*          cursor  = (int*)  take((size_t)n * 4);
  int*          rowptr  = (int*)  take((size_t)(n + 1) * 4);
  int*          csr_src = (int*)  take((size_t)ne * 4);
  unsigned int* Ybf     = (unsigned int*)take((size_t)n * (NCOL / 2) * 4);
  float*        H       = (float*)take((size_t)n * NCOL * 4);
  float*        pool    = (float*)take(4096 * 4);
  int*          startg  = (int*)  take(64 * 4);
  int*          endg    = (int*)  take(64 * 4);
  int*          tsum    = (int*)  take(16384 * 4);
  int*          toff    = (int*)  take(16384 * 4);

  hipMemsetAsync(degi, 0, (size_t)n * 4, stream);
  hipMemsetAsync(pool, 0, 4096 * 4, stream);
  hipMemsetAsync(startg, 0, 64 * 4, stream);
  hipMemsetAsync(endg, 0, 64 * 4, stream);

  int nb256 = (n + 255) / 256;
  int nthreads = (n + SCAN_C - 1) / SCAN_C;
  int nbScan = (nthreads + 255) / 256;

  // CSR build (shared by both layers); XCD-partitioned atomics/writes
  deg_part<<<2048, 256, 0, stream>>>(dstI, degi, ne, n);
  bounds_kernel<<<nb256, 256, 0, stream>>>(batch, startg, endg, n);
  dinv_kernel<<<nb256, 256, 0, stream>>>(degi, dinv, n);
  scan_part<<<nbScan, 256, 0, stream>>>(degi, tsum, n, nthreads);
  scan_mid<<<1, 1024, 0, stream>>>(tsum, toff, nthreads);
  scan_fill<<<nbScan, 256, 0, stream>>>(degi, toff, rowptr, cursor, n, nthreads);
  csr_fill_part<<<2048, 256, 0, stream>>>(srcI, dstI, cursor, csr_src, ne, n);

  int nbAgg = (n * 64 + 255) / 256;
  int nbGemm = (n + 63) / 64;

  // layer 1: Ybf = bf16((x@W1)*dinv) ; H = relu(dinv*(Y_self + sum Y[src]) + b1)
  gemm_tiled<128><<<nbGemm, 256, 0, stream>>>(x, W1, dinv, Ybf, n);
  aggregate<true><<<nbAgg, 256, 0, stream>>>(rowptr, csr_src, Ybf, dinv, b1, H, n);

  // layer 2: Ybf = bf16((H@W2)*dinv) ; H = dinv*(Y_self + sum Y[src]) + b2
  gemm_tiled<64><<<nbGemm, 256, 0, stream>>>(H, W2, dinv, Ybf, n);
  aggregate<false><<<nbAgg, 256, 0, stream>>>(rowptr, csr_src, Ybf, dinv, b2, H, n);

  // pool + head
  int ngroups = (n + NPG - 1) / NPG;
  int pblocks = (ngroups * 64 + 255) / 256;
  pool_kernel<<<pblocks, 256, 0, stream>>>(H, batch, pool, n);
  final_kernel<<<1, 384, 0, stream>>>(pool, startg, endg, Wl, bl, out, ng);
}

// Round 11
// 278.495 us; speedup vs baseline: 1.5359x; 1.5202x over previous
//
#include <hip/hip_runtime.h>

#define NCOL 64
#define BSH 8                 // 256 dst nodes per bucket
#define NBMAX 512             // padded bucket count (scan width)
#define EPB 2048              // edges per P1 block
#define P2CAP 6144            // LDS out-stage entries (bucket avg 4096, +32 sigma)

// ---------------- bf16 helpers (RNE pack, bit-shift unpack) ----------------

__device__ __forceinline__ unsigned int bf16pair(float a, float b) {
  unsigned int ua = __float_as_uint(a), ub = __float_as_uint(b);
  ua = (ua + 0x7FFFu + ((ua >> 16) & 1u)) >> 16;
  ub = (ub + 0x7FFFu + ((ub >> 16) & 1u)) >> 16;
  return (ub << 16) | ua;
}
__device__ __forceinline__ float bf_lo(unsigned int v) { return __uint_as_float(v << 16); }
__device__ __forceinline__ float bf_hi(unsigned int v) { return __uint_as_float(v & 0xFFFF0000u); }

// ---------------- P1: block-local counting sort of edges by dst bucket ----------------
// Entry pack: (dst&255)<<17 | src   (src < 2^17 on this problem: n = 100000)
// All global writes coalesced: stage[] flushed linearly + one offsets row.

__global__ __launch_bounds__(256) void bin_p1(const int* __restrict__ src,
                                              const int* __restrict__ dst,
                                              unsigned int* __restrict__ ent,
                                              int* __restrict__ blockOff,
                                              int ne, int nb) {
  __shared__ int hist[NBMAX];
  __shared__ int base[NBMAX];
  __shared__ int part[256];
  __shared__ unsigned int stage[EPB];
  int tid = threadIdx.x;
  int e0 = blockIdx.x * EPB;
  int cnt = min(EPB, ne - e0);

  for (int i = tid; i < NBMAX; i += 256) hist[i] = 0;
  __syncthreads();
  for (int i = tid; i < cnt; i += 256) {
    int d = dst[e0 + i];
    atomicAdd(&hist[d >> BSH], 1);
  }
  __syncthreads();

  // exclusive scan of hist[0..512): 2 slots/thread + Hillis-Steele over 256 partials
  int a0 = hist[2 * tid], a1 = hist[2 * tid + 1];
  int s = a0 + a1;
  part[tid] = s;
  __syncthreads();
  for (int d = 1; d < 256; d <<= 1) {
    int v = (tid >= d) ? part[tid - d] : 0;
    __syncthreads();
    part[tid] += v;
    __syncthreads();
  }
  int off = part[tid] - s;
  base[2 * tid] = off;
  base[2 * tid + 1] = off + a0;
  __syncthreads();

  // per-block bucket offsets (coalesced row) + reset hist to base as running cursor
  for (int b = tid; b < nb; b += 256) blockOff[(size_t)blockIdx.x * nb + b] = base[b];
  for (int i = tid; i < NBMAX; i += 256) hist[i] = base[i];
  __syncthreads();

  // reorder into LDS stage
  for (int i = tid; i < cnt; i += 256) {
    int d = dst[e0 + i];
    int sv = src[e0 + i];
    unsigned int e = ((unsigned int)(d & ((1 << BSH) - 1)) << 17) | (unsigned int)sv;
    int p = atomicAdd(&hist[d >> BSH], 1);
    stage[p] = e;
  }
  __syncthreads();
  // coalesced flush
  for (int i = tid; i < cnt; i += 256) ent[e0 + i] = stage[i];
}

// ---------------- degree from binned entries (LDS counters, coalesced writes) ----------------

__global__ __launch_bounds__(256) void deg_bin(const unsigned int* __restrict__ ent,
                                               const int* __restrict__ blockOff,
                                               int* __restrict__ degi,
                                               int n, int ne, int nb, int nblk) {
  __shared__ int cnt[256];
  int b = blockIdx.x;
  int tid = threadIdx.x;
  cnt[tid] = 0;
  __syncthreads();
  for (int blk = tid; blk < nblk; blk += 256) {
    int e0 = blk * EPB;
    int bcnt = min(EPB, ne - e0);
    int st = blockOff[(size_t)blk * nb + b];
    int en = (b + 1 < nb) ? blockOff[(size_t)blk * nb + b + 1] : bcnt;
    for (int i = st; i < en; ++i) {
      unsigned int e = ent[e0 + i];
      atomicAdd(&cnt[e >> 17], 1);
    }
  }
  __syncthreads();
  int node = (b << BSH) + tid;
  if (node < n) degi[node] = cnt[tid];
}

__global__ void dinv_kernel(const int* __restrict__ degi, float* __restrict__ dinv, int n) {
  int i = blockIdx.x * blockDim.x + threadIdx.x;
  if (i < n) dinv[i] = rsqrtf((float)degi[i] + 1.0f);
}

// ---------------- graph-run boundaries (batch is SORTED -> no atomics) ----------------

__global__ void bounds_kernel(const int* __restrict__ batch, int* __restrict__ startg,
                              int* __restrict__ endg, int n) {
  int i = blockIdx.x * blockDim.x + threadIdx.x;
  if (i >= n) return;
  int b = batch[i];
  if (i == 0) {
    startg[b] = 0;
  } else {
    int bp = batch[i - 1];
    if (b != bp) { startg[b] = i; endg[bp] = i; }
  }
  if (i == n - 1) endg[b] = n;
}

// ---------------- 3-pass exclusive scan of degrees -> rowptr[0..n] ----------------

#define SCAN_C 8

__global__ void scan_part(const int* __restrict__ degi, int* __restrict__ tsum,
                          int n, int nthreads) {
  int t = blockIdx.x * blockDim.x + threadIdx.x;
  if (t >= nthreads) return;
  int lo = t * SCAN_C, hi = min(lo + SCAN_C, n);
  int s = 0;
  for (int i = lo; i < hi; ++i) s += degi[i];
  tsum[t] = s;
}

__global__ void scan_mid(int* __restrict__ tsum, int* __restrict__ toff, int nthreads) {
  __shared__ int part[1024];
  int t = threadIdx.x;
  int chunk = (nthreads + 1023) >> 10;
  int lo = t * chunk, hi = min(lo + chunk, nthreads);
  int s = 0;
  for (int i = lo; i < hi; ++i) s += tsum[i];
  part[t] = s;
  __syncthreads();
  for (int d = 1; d < 1024; d <<= 1) {
    int v = (t >= d) ? part[t - d] : 0;
    __syncthreads();
    part[t] += v;
    __syncthreads();
  }
  int off = part[t] - s;
  for (int i = lo; i < hi; ++i) { toff[i] = off; off += tsum[i]; }
}

__global__ void scan_fill(const int* __restrict__ degi, const int* __restrict__ toff,
                          int* __restrict__ rowptr, int n, int nthreads) {
  int t = blockIdx.x * blockDim.x + threadIdx.x;
  if (t >= nthreads) return;
  int lo = t * SCAN_C, hi = min(lo + SCAN_C, n);
  int off = toff[t];
  for (int i = lo; i < hi; ++i) {
    rowptr[i] = off;
    off += degi[i];
  }
  if (hi == n) rowptr[n] = off;
}

// ---------------- P2: bucket-local LDS scatter -> node-grouped CSR ----------------
// One block per bucket. Per-node LDS cursors (rowptr-relative); scatter into
// LDS out-stage; single coalesced flush. Overflow (>P2CAP) falls back to
// direct global stores (correct, never expected on this input).

__global__ __launch_bounds__(256) void bin_p2(const unsigned int* __restrict__ ent,
                                              const int* __restrict__ blockOff,
                                              const int* __restrict__ rowptr,
                                              int* __restrict__ csr_src,
                                              int n, int ne, int nb, int nblk) {
  __shared__ int cur[256];
  __shared__ int outS[P2CAP];
  int b = blockIdx.x;
  int tid = threadIdx.x;
  int node0 = b << BSH;
  int node1 = min(node0 + 256, n);
  int bucketBase = rowptr[node0];
  int bucketCnt = rowptr[node1] - bucketBase;
  int node = node0 + tid;
  cur[tid] = (node < node1) ? (rowptr[node] - bucketBase) : 0;
  __syncthreads();
  for (int blk = tid; blk < nblk; blk += 256) {
    int e0 = blk * EPB;
    int bcnt = min(EPB, ne - e0);
    int st = blockOff[(size_t)blk * nb + b];
    int en = (b + 1 < nb) ? blockOff[(size_t)blk * nb + b + 1] : bcnt;
    for (int i = st; i < en; ++i) {
      unsigned int e = ent[e0 + i];
      int dL = e >> 17;
      int sv = (int)(e & 0x1FFFFu);
      int p = atomicAdd(&cur[dL], 1);
      if (p < P2CAP) outS[p] = sv;
      else csr_src[bucketBase + p] = sv;   // rare overflow fallback
    }
  }
  __syncthreads();
  int lim = min(bucketCnt, P2CAP);
  for (int i = tid; i < lim; i += 256) csr_src[bucketBase + i] = outS[i];
}

// ---------------- tiled tall-skinny GEMM -> bf16 messages ----------------

template<int K>
__global__ __launch_bounds__(256, 4) void gemm_tiled(
    const float* __restrict__ X, const float* __restrict__ W,
    const float* __restrict__ dinv, unsigned int* __restrict__ Ybf, int n) {
  __shared__ float XS[64][K + 1];
  int tid = threadIdx.x;
  int rows0 = blockIdx.x * 64;

  const int K4 = K / 4;
  for (int f = tid; f < 64 * K4; f += 256) {
    int r = f / K4, k4 = (f % K4) * 4;
    int gr = min(rows0 + r, n - 1);
    float4 v = *reinterpret_cast<const float4*>(X + (size_t)gr * K + k4);
    XS[r][k4 + 0] = v.x; XS[r][k4 + 1] = v.y;
    XS[r][k4 + 2] = v.z; XS[r][k4 + 3] = v.w;
  }
  __syncthreads();

  int lane = tid & 63;
  int cgrp = __builtin_amdgcn_readfirstlane(tid >> 6);
  int gr = rows0 + lane;

  float acc[16];
#pragma unroll
  for (int c = 0; c < 16; ++c) acc[c] = 0.f;

  const float* wbase = W + cgrp * 16;
#pragma unroll 4
  for (int k = 0; k < K; ++k) {
    float xk = XS[lane][k];
    const float* wr = wbase + (size_t)k * NCOL;
#pragma unroll
    for (int c = 0; c < 16; c += 4) {
      float4 wv = *reinterpret_cast<const float4*>(wr + c);
      acc[c + 0] = fmaf(xk, wv.x, acc[c + 0]);
      acc[c + 1] = fmaf(xk, wv.y, acc[c + 1]);
      acc[c + 2] = fmaf(xk, wv.z, acc[c + 2]);
      acc[c + 3] = fmaf(xk, wv.w, acc[c + 3]);
    }
  }

  if (gr < n) {
    float d = dinv[gr];
    unsigned int* yr = Ybf + (size_t)gr * (NCOL / 2) + cgrp * 8;
    uint4 o0, o1;
    o0.x = bf16pair(acc[0] * d,  acc[1] * d);
    o0.y = bf16pair(acc[2] * d,  acc[3] * d);
    o0.z = bf16pair(acc[4] * d,  acc[5] * d);
    o0.w = bf16pair(acc[6] * d,  acc[7] * d);
    o1.x = bf16pair(acc[8] * d,  acc[9] * d);
    o1.y = bf16pair(acc[10] * d, acc[11] * d);
    o1.z = bf16pair(acc[12] * d, acc[13] * d);
    o1.w = bf16pair(acc[14] * d, acc[15] * d);
    *reinterpret_cast<uint4*>(yr) = o0;
    *reinterpret_cast<uint4*>(yr + 4) = o1;
  }
}

// ---------------- CSR gather-aggregate over bf16 messages ----------------

template<bool RELU>
__global__ void aggregate(const int* __restrict__ rowptr, const int* __restrict__ csr_src,
                          const unsigned int* __restrict__ Ybf, const float* __restrict__ dinv,
                          const float* __restrict__ bias, float* __restrict__ H, int n) {
  int nd = (blockIdx.x * blockDim.x + threadIdx.x) >> 6;
  if (nd >= n) return;
  nd = __builtin_amdgcn_readfirstlane(nd);
  int lane = threadIdx.x & 63;
  int c2 = lane & 31;
  int half = lane >> 5;
  int lo = rowptr[nd], hi = rowptr[nd + 1];
  float ax = 0.f, ay = 0.f;
  if (half == 0) {
    unsigned int v = Ybf[(size_t)nd * 32 + c2];
    ax = bf_lo(v); ay = bf_hi(v);
  }
  int p = lo + half;
  for (; p + 6 < hi; p += 8) {
    int s0 = csr_src[p],     s1 = csr_src[p + 2];
    int s2 = csr_src[p + 4], s3 = csr_src[p + 6];
    unsigned int v0 = Ybf[(size_t)s0 * 32 + c2];
    unsigned int v1 = Ybf[(size_t)s1 * 32 + c2];
    unsigned int v2 = Ybf[(size_t)s2 * 32 + c2];
    unsigned int v3 = Ybf[(size_t)s3 * 32 + c2];
    ax += bf_lo(v0); ay += bf_hi(v0);
    ax += bf_lo(v1); ay += bf_hi(v1);
    ax += bf_lo(v2); ay += bf_hi(v2);
    ax += bf_lo(v3); ay += bf_hi(v3);
  }
  for (; p < hi; p += 2) {
    unsigned int v = Ybf[(size_t)csr_src[p] * 32 + c2];
    ax += bf_lo(v); ay += bf_hi(v);
  }
  ax += __shfl_xor(ax, 32);
  ay += __shfl_xor(ay, 32);
  if (half == 0) {
    float d = dinv[nd];
    float vx = fmaf(d, ax, bias[2 * c2]);
    float vy = fmaf(d, ay, bias[2 * c2 + 1]);
    if (RELU) { vx = fmaxf(vx, 0.f); vy = fmaxf(vy, 0.f); }
    reinterpret_cast<float2*>(H)[(size_t)nd * 32 + c2] = make_float2(vx, vy);
  }
}

// ---------------- pooling: pool[g,:] += H over sorted batch runs ----------------

#define NPG 64

__global__ void pool_kernel(const float* __restrict__ H, const int* __restrict__ batch,
                            float* __restrict__ pool, int n) {
  int gid = (blockIdx.x * blockDim.x + threadIdx.x) >> 6;
  int c = threadIdx.x & 63;
  int n0 = gid * NPG;
  if (n0 >= n) return;
  int n1 = min(n0 + NPG, n);
  float acc = 0.f;
  int curg = batch[n0];
  for (int nd = n0; nd < n1; ++nd) {
    int g = batch[nd];
    if (g != curg) {
      atomicAdd(&pool[(size_t)curg * NCOL + c], acc);
      acc = 0.f;
      curg = g;
    }
    acc += H[(size_t)nd * NCOL + c];
  }
  atomicAdd(&pool[(size_t)curg * NCOL + c], acc);
}

// ---------------- final tiny GEMM: out = (pool/cnt) @ Wl + bl ----------------

__global__ void final_kernel(const float* __restrict__ pool, const int* __restrict__ startg,
                             const int* __restrict__ endg, const float* __restrict__ Wl,
                             const float* __restrict__ bl, float* __restrict__ out, int ng) {
  int t = threadIdx.x;
  if (t >= ng * 6) return;
  int g = t / 6, o = t % 6;
  float cntf = (float)(endg[g] - startg[g]);
  float inv = 1.0f / fmaxf(cntf, 1.0f);
  float s = 0.f;
#pragma unroll
  for (int c = 0; c < NCOL; ++c) s += pool[(size_t)g * NCOL + c] * Wl[c * 6 + o];
  out[t] = fmaf(s, inv, bl[o]);
}

// ---------------- launch ----------------

extern "C" void kernel_launch(void* const* d_in, const int* in_sizes, int n_in,
                              void* d_out, int out_size, void* d_ws, size_t ws_size,
                              hipStream_t stream) {
  const float* x    = (const float*)d_in[0];
  const int*   ei   = (const int*)d_in[1];
  const int*   batch= (const int*)d_in[2];
  const float* W1   = (const float*)d_in[3];
  const float* b1   = (const float*)d_in[4];
  const float* W2   = (const float*)d_in[5];
  const float* b2   = (const float*)d_in[6];
  const float* Wl   = (const float*)d_in[7];
  const float* bl   = (const float*)d_in[8];
  float* out = (float*)d_out;

  int n  = in_sizes[0] / 128;   // 100000
  int ne = in_sizes[1] / 2;     // 1600000
  int ng = out_size / 6;        // 64
  const int* srcI = ei;
  const int* dstI = ei + ne;

  int nb   = (n + 255) >> BSH;            // 391 buckets
  int nblk = (ne + EPB - 1) / EPB;        // 782 P1 blocks

  char* w = (char*)d_ws;
  size_t o = 0;
  auto take = [&](size_t bytes) -> char* {
    char* p = w + o;
    o = (o + bytes + 255) & ~(size_t)255;
    return p;
  };
  float*        dinv    = (float*)take((size_t)n * 4);
  int*          degi    = (int*)  take((size_t)n * 4);
  int*          rowptr  = (int*)  take((size_t)(n + 1) * 4);
  int*          csr_src = (int*)  take((size_t)ne * 4);
  unsigned int* ent     = (unsigned int*)take((size_t)ne * 4);
  int*          blockOff= (int*)  take((size_t)nblk * nb * 4);
  unsigned int* Ybf     = (unsigned int*)take((size_t)n * (NCOL / 2) * 4);
  float*        H       = (float*)take((size_t)n * NCOL * 4);
  float*        pool    = (float*)take(4096 * 4);
  int*          startg  = (int*)  take(64 * 4);
  int*          endg    = (int*)  take(64 * 4);
  int*          tsum    = (int*)  take(16384 * 4);
  int*          toff    = (int*)  take(16384 * 4);

  hipMemsetAsync(pool, 0, 4096 * 4, stream);
  hipMemsetAsync(startg, 0, 64 * 4, stream);
  hipMemsetAsync(endg, 0, 64 * 4, stream);

  int nb256 = (n + 255) / 256;
  int nthreads = (n + SCAN_C - 1) / SCAN_C;
  int nbScan = (nthreads + 255) / 256;

  // CSR build via two-phase LDS binning (all global writes coalesced)
  bin_p1<<<nblk, 256, 0, stream>>>(srcI, dstI, ent, blockOff, ne, nb);
  deg_bin<<<nb, 256, 0, stream>>>(ent, blockOff, degi, n, ne, nb, nblk);
  bounds_kernel<<<nb256, 256, 0, stream>>>(batch, startg, endg, n);
  dinv_kernel<<<nb256, 256, 0, stream>>>(degi, dinv, n);
  scan_part<<<nbScan, 256, 0, stream>>>(degi, tsum, n, nthreads);
  scan_mid<<<1, 1024, 0, stream>>>(tsum, toff, nthreads);
  scan_fill<<<nbScan, 256, 0, stream>>>(degi, toff, rowptr, n, nthreads);
  bin_p2<<<nb, 256, 0, stream>>>(ent, blockOff, rowptr, csr_src, n, ne, nb, nblk);

  int nbAgg = (n * 64 + 255) / 256;
  int nbGemm = (n + 63) / 64;

  // layer 1: Ybf = bf16((x@W1)*dinv) ; H = relu(dinv*(Y_self + sum Y[src]) + b1)
  gemm_tiled<128><<<nbGemm, 256, 0, stream>>>(x, W1, dinv, Ybf, n);
  aggregate<true><<<nbAgg, 256, 0, stream>>>(rowptr, csr_src, Ybf, dinv, b1, H, n);

  // layer 2: Ybf = bf16((H@W2)*dinv) ; H = dinv*(Y_self + sum Y[src]) + b2
  gemm_tiled<64><<<nbGemm, 256, 0, stream>>>(H, W2, dinv, Ybf, n);
  aggregate<false><<<nbAgg, 256, 0, stream>>>(rowptr, csr_src, Ybf, dinv, b2, H, n);

  // pool + head
  int ngroups = (n + NPG - 1) / NPG;
  int pblocks = (ngroups * 64 + 255) / 256;
  pool_kernel<<<pblocks, 256, 0, stream>>>(H, batch, pool, n);
  final_kernel<<<1, 384, 0, stream>>>(pool, startg, endg, Wl, bl, out, ng);
}

// Round 12
// 265.391 us; speedup vs baseline: 1.6117x; 1.0494x over previous
//
#include <hip/hip_runtime.h>

#define NCOL 64
#define BSH 8                 // 256 dst nodes per bucket
#define NBMAX 512             // padded bucket count (scan width)
#define EPB 2048              // edges per P1 block
#define P2CAP 6144            // LDS out-stage entries (bucket avg 4096, +32 sigma)

// ---------------- bf16 helpers (RNE pack, bit-shift unpack) ----------------

__device__ __forceinline__ unsigned int bf16pair(float a, float b) {
  unsigned int ua = __float_as_uint(a), ub = __float_as_uint(b);
  ua = (ua + 0x7FFFu + ((ua >> 16) & 1u)) >> 16;
  ub = (ub + 0x7FFFu + ((ub >> 16) & 1u)) >> 16;
  return (ub << 16) | ua;
}
__device__ __forceinline__ float bf_lo(unsigned int v) { return __uint_as_float(v << 16); }
__device__ __forceinline__ float bf_hi(unsigned int v) { return __uint_as_float(v & 0xFFFF0000u); }

// ---------------- P1: block-local counting sort of edges by dst bucket ----------------
// Entry pack: (dst&255)<<17 | src   (src < 2^17 on this problem: n = 100000)

__global__ __launch_bounds__(256) void bin_p1(const int* __restrict__ src,
                                              const int* __restrict__ dst,
                                              unsigned int* __restrict__ ent,
                                              int* __restrict__ blockOff,
                                              int ne, int nb) {
  __shared__ int hist[NBMAX];
  __shared__ int base[NBMAX];
  __shared__ int part[256];
  __shared__ unsigned int stage[EPB];
  int tid = threadIdx.x;
  int e0 = blockIdx.x * EPB;
  int cnt = min(EPB, ne - e0);

  for (int i = tid; i < NBMAX; i += 256) hist[i] = 0;
  __syncthreads();
  for (int i = tid; i < cnt; i += 256) {
    int d = dst[e0 + i];
    atomicAdd(&hist[d >> BSH], 1);
  }
  __syncthreads();

  int a0 = hist[2 * tid], a1 = hist[2 * tid + 1];
  int s = a0 + a1;
  part[tid] = s;
  __syncthreads();
  for (int d = 1; d < 256; d <<= 1) {
    int v = (tid >= d) ? part[tid - d] : 0;
    __syncthreads();
    part[tid] += v;
    __syncthreads();
  }
  int off = part[tid] - s;
  base[2 * tid] = off;
  base[2 * tid + 1] = off + a0;
  __syncthreads();

  for (int b = tid; b < nb; b += 256) blockOff[(size_t)blockIdx.x * nb + b] = base[b];
  for (int i = tid; i < NBMAX; i += 256) hist[i] = base[i];
  __syncthreads();

  for (int i = tid; i < cnt; i += 256) {
    int d = dst[e0 + i];
    int sv = src[e0 + i];
    unsigned int e = ((unsigned int)(d & ((1 << BSH) - 1)) << 17) | (unsigned int)sv;
    int p = atomicAdd(&hist[d >> BSH], 1);
    stage[p] = e;
  }
  __syncthreads();
  for (int i = tid; i < cnt; i += 256) ent[e0 + i] = stage[i];
}

// ---------------- degree from binned entries (LDS counters, coalesced writes) ----------------

__global__ __launch_bounds__(256) void deg_bin(const unsigned int* __restrict__ ent,
                                               const int* __restrict__ blockOff,
                                               int* __restrict__ degi,
                                               int n, int ne, int nb, int nblk) {
  __shared__ int cnt[256];
  int b = blockIdx.x;
  int tid = threadIdx.x;
  cnt[tid] = 0;
  __syncthreads();
  for (int blk = tid; blk < nblk; blk += 256) {
    int e0 = blk * EPB;
    int bcnt = min(EPB, ne - e0);
    int st = blockOff[(size_t)blk * nb + b];
    int en = (b + 1 < nb) ? blockOff[(size_t)blk * nb + b + 1] : bcnt;
    for (int i = st; i < en; ++i) {
      unsigned int e = ent[e0 + i];
      atomicAdd(&cnt[e >> 17], 1);
    }
  }
  __syncthreads();
  int node = (b << BSH) + tid;
  if (node < n) degi[node] = cnt[tid];
}

__global__ void dinv_kernel(const int* __restrict__ degi, float* __restrict__ dinv, int n) {
  int i = blockIdx.x * blockDim.x + threadIdx.x;
  if (i < n) dinv[i] = rsqrtf((float)degi[i] + 1.0f);
}

// ---------------- graph-run boundaries (batch is SORTED -> no atomics) ----------------

__global__ void bounds_kernel(const int* __restrict__ batch, int* __restrict__ startg,
                              int* __restrict__ endg, int n) {
  int i = blockIdx.x * blockDim.x + threadIdx.x;
  if (i >= n) return;
  int b = batch[i];
  if (i == 0) {
    startg[b] = 0;
  } else {
    int bp = batch[i - 1];
    if (b != bp) { startg[b] = i; endg[bp] = i; }
  }
  if (i == n - 1) endg[b] = n;
}

// ---------------- 3-pass exclusive scan of degrees -> rowptr[0..n] ----------------

#define SCAN_C 8

__global__ void scan_part(const int* __restrict__ degi, int* __restrict__ tsum,
                          int n, int nthreads) {
  int t = blockIdx.x * blockDim.x + threadIdx.x;
  if (t >= nthreads) return;
  int lo = t * SCAN_C, hi = min(lo + SCAN_C, n);
  int s = 0;
  for (int i = lo; i < hi; ++i) s += degi[i];
  tsum[t] = s;
}

__global__ void scan_mid(int* __restrict__ tsum, int* __restrict__ toff, int nthreads) {
  __shared__ int part[1024];
  int t = threadIdx.x;
  int chunk = (nthreads + 1023) >> 10;
  int lo = t * chunk, hi = min(lo + chunk, nthreads);
  int s = 0;
  for (int i = lo; i < hi; ++i) s += tsum[i];
  part[t] = s;
  __syncthreads();
  for (int d = 1; d < 1024; d <<= 1) {
    int v = (t >= d) ? part[t - d] : 0;
    __syncthreads();
    part[t] += v;
    __syncthreads();
  }
  int off = part[t] - s;
  for (int i = lo; i < hi; ++i) { toff[i] = off; off += tsum[i]; }
}

__global__ void scan_fill(const int* __restrict__ degi, const int* __restrict__ toff,
                          int* __restrict__ rowptr, int n, int nthreads) {
  int t = blockIdx.x * blockDim.x + threadIdx.x;
  if (t >= nthreads) return;
  int lo = t * SCAN_C, hi = min(lo + SCAN_C, n);
  int off = toff[t];
  for (int i = lo; i < hi; ++i) {
    rowptr[i] = off;
    off += degi[i];
  }
  if (hi == n) rowptr[n] = off;
}

// ---------------- P2: bucket-local LDS scatter -> node-grouped CSR ----------------

__global__ __launch_bounds__(256) void bin_p2(const unsigned int* __restrict__ ent,
                                              const int* __restrict__ blockOff,
                                              const int* __restrict__ rowptr,
                                              int* __restrict__ csr_src,
                                              int n, int ne, int nb, int nblk) {
  __shared__ int cur[256];
  __shared__ int outS[P2CAP];
  int b = blockIdx.x;
  int tid = threadIdx.x;
  int node0 = b << BSH;
  int node1 = min(node0 + 256, n);
  int bucketBase = rowptr[node0];
  int bucketCnt = rowptr[node1] - bucketBase;
  int node = node0 + tid;
  cur[tid] = (node < node1) ? (rowptr[node] - bucketBase) : 0;
  __syncthreads();
  for (int blk = tid; blk < nblk; blk += 256) {
    int e0 = blk * EPB;
    int bcnt = min(EPB, ne - e0);
    int st = blockOff[(size_t)blk * nb + b];
    int en = (b + 1 < nb) ? blockOff[(size_t)blk * nb + b + 1] : bcnt;
    for (int i = st; i < en; ++i) {
      unsigned int e = ent[e0 + i];
      int dL = e >> 17;
      int sv = (int)(e & 0x1FFFFu);
      int p = atomicAdd(&cur[dL], 1);
      if (p < P2CAP) outS[p] = sv;
      else csr_src[bucketBase + p] = sv;   // rare overflow fallback
    }
  }
  __syncthreads();
  int lim = min(bucketCnt, P2CAP);
  for (int i = tid; i < lim; i += 256) csr_src[bucketBase + i] = outS[i];
}

// ---------------- tiled tall-skinny GEMM -> bf16 messages ----------------

template<int K>
__global__ __launch_bounds__(256, 4) void gemm_tiled(
    const float* __restrict__ X, const float* __restrict__ W,
    const float* __restrict__ dinv, unsigned int* __restrict__ Ybf, int n) {
  __shared__ float XS[64][K + 1];
  int tid = threadIdx.x;
  int rows0 = blockIdx.x * 64;

  const int K4 = K / 4;
  for (int f = tid; f < 64 * K4; f += 256) {
    int r = f / K4, k4 = (f % K4) * 4;
    int gr = min(rows0 + r, n - 1);
    float4 v = *reinterpret_cast<const float4*>(X + (size_t)gr * K + k4);
    XS[r][k4 + 0] = v.x; XS[r][k4 + 1] = v.y;
    XS[r][k4 + 2] = v.z; XS[r][k4 + 3] = v.w;
  }
  __syncthreads();

  int lane = tid & 63;
  int cgrp = __builtin_amdgcn_readfirstlane(tid >> 6);
  int gr = rows0 + lane;

  float acc[16];
#pragma unroll
  for (int c = 0; c < 16; ++c) acc[c] = 0.f;

  const float* wbase = W + cgrp * 16;
#pragma unroll 4
  for (int k = 0; k < K; ++k) {
    float xk = XS[lane][k];
    const float* wr = wbase + (size_t)k * NCOL;
#pragma unroll
    for (int c = 0; c < 16; c += 4) {
      float4 wv = *reinterpret_cast<const float4*>(wr + c);
      acc[c + 0] = fmaf(xk, wv.x, acc[c + 0]);
      acc[c + 1] = fmaf(xk, wv.y, acc[c + 1]);
      acc[c + 2] = fmaf(xk, wv.z, acc[c + 2]);
      acc[c + 3] = fmaf(xk, wv.w, acc[c + 3]);
    }
  }

  if (gr < n) {
    float d = dinv[gr];
    unsigned int* yr = Ybf + (size_t)gr * (NCOL / 2) + cgrp * 8;
    uint4 o0, o1;
    o0.x = bf16pair(acc[0] * d,  acc[1] * d);
    o0.y = bf16pair(acc[2] * d,  acc[3] * d);
    o0.z = bf16pair(acc[4] * d,  acc[5] * d);
    o0.w = bf16pair(acc[6] * d,  acc[7] * d);
    o1.x = bf16pair(acc[8] * d,  acc[9] * d);
    o1.y = bf16pair(acc[10] * d, acc[11] * d);
    o1.z = bf16pair(acc[12] * d, acc[13] * d);
    o1.w = bf16pair(acc[14] * d, acc[15] * d);
    *reinterpret_cast<uint4*>(yr) = o0;
    *reinterpret_cast<uint4*>(yr + 4) = o1;
  }
}

// ---------------- CSR gather-aggregate over bf16 messages ----------------
// Wave per dst node. 8 groups x 8 lanes: group g handles edges p+g, lane l
// loads uint4 (cols 8l..8l+8) -> 8 independent 128B gathers in flight/iter.
// Cross-group butterfly reduce (shfl_xor 8/16/32); group 0 finalizes + writes.

template<bool RELU>
__global__ __launch_bounds__(256) void aggregate(
    const int* __restrict__ rowptr, const int* __restrict__ csr_src,
    const uint4* __restrict__ Ybf4, const float* __restrict__ dinv,
    const float* __restrict__ bias, float* __restrict__ H, int n) {
  int nd = (blockIdx.x * blockDim.x + threadIdx.x) >> 6;
  if (nd >= n) return;
  nd = __builtin_amdgcn_readfirstlane(nd);
  int lane = threadIdx.x & 63;
  int l = lane & 7;        // uint4 slot within row (cols 8l..8l+8)
  int g = lane >> 3;       // edge subgroup 0..7
  int lo = rowptr[nd], hi = rowptr[nd + 1];

  float a0 = 0.f, a1 = 0.f, a2 = 0.f, a3 = 0.f,
        a4 = 0.f, a5 = 0.f, a6 = 0.f, a7 = 0.f;

  for (int p = lo + g; p < hi; p += 8) {
    int s = csr_src[p];
    uint4 v = Ybf4[(size_t)s * 8 + l];
    a0 += bf_lo(v.x); a1 += bf_hi(v.x);
    a2 += bf_lo(v.y); a3 += bf_hi(v.y);
    a4 += bf_lo(v.z); a5 += bf_hi(v.z);
    a6 += bf_lo(v.w); a7 += bf_hi(v.w);
  }

  // reduce across the 8 groups (lane bits 3..5)
#pragma unroll
  for (int m = 8; m < 64; m <<= 1) {
    a0 += __shfl_xor(a0, m); a1 += __shfl_xor(a1, m);
    a2 += __shfl_xor(a2, m); a3 += __shfl_xor(a3, m);
    a4 += __shfl_xor(a4, m); a5 += __shfl_xor(a5, m);
    a6 += __shfl_xor(a6, m); a7 += __shfl_xor(a7, m);
  }

  if (g == 0) {
    uint4 v = Ybf4[(size_t)nd * 8 + l];   // self-loop term
    a0 += bf_lo(v.x); a1 += bf_hi(v.x);
    a2 += bf_lo(v.y); a3 += bf_hi(v.y);
    a4 += bf_lo(v.z); a5 += bf_hi(v.z);
    a6 += bf_lo(v.w); a7 += bf_hi(v.w);
    float d = dinv[nd];
    float4 b0 = *reinterpret_cast<const float4*>(bias + l * 8);
    float4 b1 = *reinterpret_cast<const float4*>(bias + l * 8 + 4);
    float4 o0, o1;
    o0.x = fmaf(d, a0, b0.x); o0.y = fmaf(d, a1, b0.y);
    o0.z = fmaf(d, a2, b0.z); o0.w = fmaf(d, a3, b0.w);
    o1.x = fmaf(d, a4, b1.x); o1.y = fmaf(d, a5, b1.y);
    o1.z = fmaf(d, a6, b1.z); o1.w = fmaf(d, a7, b1.w);
    if (RELU) {
      o0.x = fmaxf(o0.x, 0.f); o0.y = fmaxf(o0.y, 0.f);
      o0.z = fmaxf(o0.z, 0.f); o0.w = fmaxf(o0.w, 0.f);
      o1.x = fmaxf(o1.x, 0.f); o1.y = fmaxf(o1.y, 0.f);
      o1.z = fmaxf(o1.z, 0.f); o1.w = fmaxf(o1.w, 0.f);
    }
    float* hr = H + (size_t)nd * NCOL + l * 8;
    *reinterpret_cast<float4*>(hr) = o0;
    *reinterpret_cast<float4*>(hr + 4) = o1;
  }
}

// ---------------- pooling: pool[g,:] += H over sorted batch runs ----------------

#define NPG 64

__global__ void pool_kernel(const float* __restrict__ H, const int* __restrict__ batch,
                            float* __restrict__ pool, int n) {
  int gid = (blockIdx.x * blockDim.x + threadIdx.x) >> 6;
  int c = threadIdx.x & 63;
  int n0 = gid * NPG;
  if (n0 >= n) return;
  int n1 = min(n0 + NPG, n);
  float acc = 0.f;
  int curg = batch[n0];
  for (int nd = n0; nd < n1; ++nd) {
    int g = batch[nd];
    if (g != curg) {
      atomicAdd(&pool[(size_t)curg * NCOL + c], acc);
      acc = 0.f;
      curg = g;
    }
    acc += H[(size_t)nd * NCOL + c];
  }
  atomicAdd(&pool[(size_t)curg * NCOL + c], acc);
}

// ---------------- final tiny GEMM: out = (pool/cnt) @ Wl + bl ----------------

__global__ void final_kernel(const float* __restrict__ pool, const int* __restrict__ startg,
                             const int* __restrict__ endg, const float* __restrict__ Wl,
                             const float* __restrict__ bl, float* __restrict__ out, int ng) {
  int t = threadIdx.x;
  if (t >= ng * 6) return;
  int g = t / 6, o = t % 6;
  float cntf = (float)(endg[g] - startg[g]);
  float inv = 1.0f / fmaxf(cntf, 1.0f);
  float s = 0.f;
#pragma unroll
  for (int c = 0; c < NCOL; ++c) s += pool[(size_t)g * NCOL + c] * Wl[c * 6 + o];
  out[t] = fmaf(s, inv, bl[o]);
}

// ---------------- launch ----------------

extern "C" void kernel_launch(void* const* d_in, const int* in_sizes, int n_in,
                              void* d_out, int out_size, void* d_ws, size_t ws_size,
                              hipStream_t stream) {
  const float* x    = (const float*)d_in[0];
  const int*   ei   = (const int*)d_in[1];
  const int*   batch= (const int*)d_in[2];
  const float* W1   = (const float*)d_in[3];
  const float* b1   = (const float*)d_in[4];
  const float* W2   = (const float*)d_in[5];
  const float* b2   = (const float*)d_in[6];
  const float* Wl   = (const float*)d_in[7];
  const float* bl   = (const float*)d_in[8];
  float* out = (float*)d_out;

  int n  = in_sizes[0] / 128;   // 100000
  int ne = in_sizes[1] / 2;     // 1600000
  int ng = out_size / 6;        // 64
  const int* srcI = ei;
  const int* dstI = ei + ne;

  int nb   = (n + 255) >> BSH;            // 391 buckets
  int nblk = (ne + EPB - 1) / EPB;        // 782 P1 blocks

  char* w = (char*)d_ws;
  size_t o = 0;
  auto take = [&](size_t bytes) -> char* {
    char* p = w + o;
    o = (o + bytes + 255) & ~(size_t)255;
    return p;
  };
  float*        dinv    = (float*)take((size_t)n * 4);
  int*          degi    = (int*)  take((size_t)n * 4);
  int*          rowptr  = (int*)  take((size_t)(n + 1) * 4);
  int*          csr_src = (int*)  take((size_t)ne * 4);
  unsigned int* ent     = (unsigned int*)take((size_t)ne * 4);
  int*          blockOff= (int*)  take((size_t)nblk * nb * 4);
  unsigned int* Ybf     = (unsigned int*)take((size_t)n * (NCOL / 2) * 4);
  float*        H       = (float*)take((size_t)n * NCOL * 4);
  float*        pool    = (float*)take(4096 * 4);
  int*          startg  = (int*)  take(64 * 4);
  int*          endg    = (int*)  take(64 * 4);
  int*          tsum    = (int*)  take(16384 * 4);
  int*          toff    = (int*)  take(16384 * 4);

  hipMemsetAsync(pool, 0, 4096 * 4, stream);
  hipMemsetAsync(startg, 0, 64 * 4, stream);
  hipMemsetAsync(endg, 0, 64 * 4, stream);

  int nb256 = (n + 255) / 256;
  int nthreads = (n + SCAN_C - 1) / SCAN_C;
  int nbScan = (nthreads + 255) / 256;

  // CSR build via two-phase LDS binning (all global writes coalesced)
  bin_p1<<<nblk, 256, 0, stream>>>(srcI, dstI, ent, blockOff, ne, nb);
  deg_bin<<<nb, 256, 0, stream>>>(ent, blockOff, degi, n, ne, nb, nblk);
  bounds_kernel<<<nb256, 256, 0, stream>>>(batch, startg, endg, n);
  dinv_kernel<<<nb256, 256, 0, stream>>>(degi, dinv, n);
  scan_part<<<nbScan, 256, 0, stream>>>(degi, tsum, n, nthreads);
  scan_mid<<<1, 1024, 0, stream>>>(tsum, toff, nthreads);
  scan_fill<<<nbScan, 256, 0, stream>>>(degi, toff, rowptr, n, nthreads);
  bin_p2<<<nb, 256, 0, stream>>>(ent, blockOff, rowptr, csr_src, n, ne, nb, nblk);

  int nbAgg = (n * 64 + 255) / 256;
  int nbGemm = (n + 63) / 64;

  // layer 1: Ybf = bf16((x@W1)*dinv) ; H = relu(dinv*(Y_self + sum Y[src]) + b1)
  gemm_tiled<128><<<nbGemm, 256, 0, stream>>>(x, W1, dinv, Ybf, n);
  aggregate<true><<<nbAgg, 256, 0, stream>>>(rowptr, csr_src, (const uint4*)Ybf, dinv, b1, H, n);

  // layer 2: Ybf = bf16((H@W2)*dinv) ; H = dinv*(Y_self + sum Y[src]) + b2
  gemm_tiled<64><<<nbGemm, 256, 0, stream>>>(H, W2, dinv, Ybf, n);
  aggregate<false><<<nbAgg, 256, 0, stream>>>(rowptr, csr_src, (const uint4*)Ybf, dinv, b2, H, n);

  // pool + head
  int ngroups = (n + NPG - 1) / NPG;
  int pblocks = (ngroups * 64 + 255) / 256;
  pool_kernel<<<pblocks, 256, 0, stream>>>(H, batch, pool, n);
  final_kernel<<<1, 384, 0, stream>>>(pool, startg, endg, Wl, bl, out, ng);
}

// Round 13
// 256.923 us; speedup vs baseline: 1.6648x; 1.0330x over previous
//
#include <hip/hip_runtime.h>

#define NCOL 64
#define BSH 8                 // 256 dst nodes per bucket
#define NBMAX 512             // padded bucket count (scan width)
#define EPB 2048              // edges per P1 block
#define P2CAP 6144            // LDS out-stage entries (bucket avg 4096, +32 sigma)

// ---------------- bf16 helpers (RNE pack, bit-shift unpack) ----------------

__device__ __forceinline__ unsigned int bf16pair(float a, float b) {
  unsigned int ua = __float_as_uint(a), ub = __float_as_uint(b);
  ua = (ua + 0x7FFFu + ((ua >> 16) & 1u)) >> 16;
  ub = (ub + 0x7FFFu + ((ub >> 16) & 1u)) >> 16;
  return (ub << 16) | ua;
}
__device__ __forceinline__ float bf_lo(unsigned int v) { return __uint_as_float(v << 16); }
__device__ __forceinline__ float bf_hi(unsigned int v) { return __uint_as_float(v & 0xFFFF0000u); }

// ---------------- P1: block-local counting sort of edges by dst bucket ----------------
// Entry pack: (dst&255)<<17 | src   (src < 2^17 on this problem: n = 100000)

__global__ __launch_bounds__(256) void bin_p1(const int* __restrict__ src,
                                              const int* __restrict__ dst,
                                              unsigned int* __restrict__ ent,
                                              int* __restrict__ blockOff,
                                              int ne, int nb) {
  __shared__ int hist[NBMAX];
  __shared__ int base[NBMAX];
  __shared__ int part[256];
  __shared__ unsigned int stage[EPB];
  int tid = threadIdx.x;
  int e0 = blockIdx.x * EPB;
  int cnt = min(EPB, ne - e0);

  for (int i = tid; i < NBMAX; i += 256) hist[i] = 0;
  __syncthreads();
  for (int i = tid; i < cnt; i += 256) {
    int d = dst[e0 + i];
    atomicAdd(&hist[d >> BSH], 1);
  }
  __syncthreads();

  int a0 = hist[2 * tid], a1 = hist[2 * tid + 1];
  int s = a0 + a1;
  part[tid] = s;
  __syncthreads();
  for (int d = 1; d < 256; d <<= 1) {
    int v = (tid >= d) ? part[tid - d] : 0;
    __syncthreads();
    part[tid] += v;
    __syncthreads();
  }
  int off = part[tid] - s;
  base[2 * tid] = off;
  base[2 * tid + 1] = off + a0;
  __syncthreads();

  for (int b = tid; b < nb; b += 256) blockOff[(size_t)blockIdx.x * nb + b] = base[b];
  for (int i = tid; i < NBMAX; i += 256) hist[i] = base[i];
  __syncthreads();

  for (int i = tid; i < cnt; i += 256) {
    int d = dst[e0 + i];
    int sv = src[e0 + i];
    unsigned int e = ((unsigned int)(d & ((1 << BSH) - 1)) << 17) | (unsigned int)sv;
    int p = atomicAdd(&hist[d >> BSH], 1);
    stage[p] = e;
  }
  __syncthreads();
  for (int i = tid; i < cnt; i += 256) ent[e0 + i] = stage[i];
}

// ---------------- degree from binned entries (LDS counters, coalesced writes) ----------------

__global__ __launch_bounds__(256) void deg_bin(const unsigned int* __restrict__ ent,
                                               const int* __restrict__ blockOff,
                                               int* __restrict__ degi,
                                               int n, int ne, int nb, int nblk) {
  __shared__ int cnt[256];
  int b = blockIdx.x;
  int tid = threadIdx.x;
  cnt[tid] = 0;
  __syncthreads();
  for (int blk = tid; blk < nblk; blk += 256) {
    int e0 = blk * EPB;
    int bcnt = min(EPB, ne - e0);
    int st = blockOff[(size_t)blk * nb + b];
    int en = (b + 1 < nb) ? blockOff[(size_t)blk * nb + b + 1] : bcnt;
    for (int i = st; i < en; ++i) {
      unsigned int e = ent[e0 + i];
      atomicAdd(&cnt[e >> 17], 1);
    }
  }
  __syncthreads();
  int node = (b << BSH) + tid;
  if (node < n) degi[node] = cnt[tid];
}

__global__ void dinv_kernel(const int* __restrict__ degi, float* __restrict__ dinv, int n) {
  int i = blockIdx.x * blockDim.x + threadIdx.x;
  if (i < n) dinv[i] = rsqrtf((float)degi[i] + 1.0f);
}

// ---------------- graph-run boundaries (batch is SORTED -> no atomics) ----------------

__global__ void bounds_kernel(const int* __restrict__ batch, int* __restrict__ startg,
                              int* __restrict__ endg, int n) {
  int i = blockIdx.x * blockDim.x + threadIdx.x;
  if (i >= n) return;
  int b = batch[i];
  if (i == 0) {
    startg[b] = 0;
  } else {
    int bp = batch[i - 1];
    if (b != bp) { startg[b] = i; endg[bp] = i; }
  }
  if (i == n - 1) endg[b] = n;
}

// ---------------- 3-pass exclusive scan of degrees -> rowptr[0..n] ----------------

#define SCAN_C 8

__global__ void scan_part(const int* __restrict__ degi, int* __restrict__ tsum,
                          int n, int nthreads) {
  int t = blockIdx.x * blockDim.x + threadIdx.x;
  if (t >= nthreads) return;
  int lo = t * SCAN_C, hi = min(lo + SCAN_C, n);
  int s = 0;
  for (int i = lo; i < hi; ++i) s += degi[i];
  tsum[t] = s;
}

__global__ void scan_mid(int* __restrict__ tsum, int* __restrict__ toff, int nthreads) {
  __shared__ int part[1024];
  int t = threadIdx.x;
  int chunk = (nthreads + 1023) >> 10;
  int lo = t * chunk, hi = min(lo + chunk, nthreads);
  int s = 0;
  for (int i = lo; i < hi; ++i) s += tsum[i];
  part[t] = s;
  __syncthreads();
  for (int d = 1; d < 1024; d <<= 1) {
    int v = (t >= d) ? part[t - d] : 0;
    __syncthreads();
    part[t] += v;
    __syncthreads();
  }
  int off = part[t] - s;
  for (int i = lo; i < hi; ++i) { toff[i] = off; off += tsum[i]; }
}

__global__ void scan_fill(const int* __restrict__ degi, const int* __restrict__ toff,
                          int* __restrict__ rowptr, int n, int nthreads) {
  int t = blockIdx.x * blockDim.x + threadIdx.x;
  if (t >= nthreads) return;
  int lo = t * SCAN_C, hi = min(lo + SCAN_C, n);
  int off = toff[t];
  for (int i = lo; i < hi; ++i) {
    rowptr[i] = off;
    off += degi[i];
  }
  if (hi == n) rowptr[n] = off;
}

// ---------------- P2: bucket-local LDS scatter -> node-grouped CSR ----------------

__global__ __launch_bounds__(256) void bin_p2(const unsigned int* __restrict__ ent,
                                              const int* __restrict__ blockOff,
                                              const int* __restrict__ rowptr,
                                              int* __restrict__ csr_src,
                                              int n, int ne, int nb, int nblk) {
  __shared__ int cur[256];
  __shared__ int outS[P2CAP];
  int b = blockIdx.x;
  int tid = threadIdx.x;
  int node0 = b << BSH;
  int node1 = min(node0 + 256, n);
  int bucketBase = rowptr[node0];
  int bucketCnt = rowptr[node1] - bucketBase;
  int node = node0 + tid;
  cur[tid] = (node < node1) ? (rowptr[node] - bucketBase) : 0;
  __syncthreads();
  for (int blk = tid; blk < nblk; blk += 256) {
    int e0 = blk * EPB;
    int bcnt = min(EPB, ne - e0);
    int st = blockOff[(size_t)blk * nb + b];
    int en = (b + 1 < nb) ? blockOff[(size_t)blk * nb + b + 1] : bcnt;
    for (int i = st; i < en; ++i) {
      unsigned int e = ent[e0 + i];
      int dL = e >> 17;
      int sv = (int)(e & 0x1FFFFu);
      int p = atomicAdd(&cur[dL], 1);
      if (p < P2CAP) outS[p] = sv;
      else csr_src[bucketBase + p] = sv;   // rare overflow fallback
    }
  }
  __syncthreads();
  int lim = min(bucketCnt, P2CAP);
  for (int i = tid; i < lim; i += 256) csr_src[bucketBase + i] = outS[i];
}

// ---------------- tiled tall-skinny GEMM -> bf16 messages ----------------
// K staged in 64-wide panels: XS[64][65] = 16.6 KB -> up to 8 blocks/CU
// (launch_bounds 256,8 = 32 waves/CU target). Staging map r=tid>>4,
// c4=(tid&15)*4: write banks (r+4m+j)%32 cover all 32 banks 2-way (free);
// read XS[lane][k] banks (lane+k)%32 2-way (free). W via wave-uniform s_load.

template<int K>
__global__ __launch_bounds__(256, 8) void gemm_tiled(
    const float* __restrict__ X, const float* __restrict__ W,
    const float* __restrict__ dinv, unsigned int* __restrict__ Ybf, int n) {
  __shared__ float XS[64][65];
  int tid = threadIdx.x;
  int rows0 = blockIdx.x * 64;
  int lane = tid & 63;
  int cgrp = __builtin_amdgcn_readfirstlane(tid >> 6);
  int gr = rows0 + lane;

  float acc[16];
#pragma unroll
  for (int c = 0; c < 16; ++c) acc[c] = 0.f;

  for (int ks = 0; ks < K; ks += 64) {
    if (ks) __syncthreads();   // protect restage
    int r0 = tid >> 4;
    int c4 = (tid & 15) * 4;
#pragma unroll
    for (int it = 0; it < 4; ++it) {
      int r = r0 + it * 16;
      int gr2 = min(rows0 + r, n - 1);
      float4 v = *reinterpret_cast<const float4*>(X + (size_t)gr2 * K + ks + c4);
      XS[r][c4 + 0] = v.x; XS[r][c4 + 1] = v.y;
      XS[r][c4 + 2] = v.z; XS[r][c4 + 3] = v.w;
    }
    __syncthreads();

    const float* wbase = W + (size_t)ks * NCOL + cgrp * 16;
#pragma unroll 4
    for (int k = 0; k < 64; ++k) {
      float xk = XS[lane][k];
      const float* wr = wbase + (size_t)k * NCOL;
#pragma unroll
      for (int c = 0; c < 16; c += 4) {
        float4 wv = *reinterpret_cast<const float4*>(wr + c);
        acc[c + 0] = fmaf(xk, wv.x, acc[c + 0]);
        acc[c + 1] = fmaf(xk, wv.y, acc[c + 1]);
        acc[c + 2] = fmaf(xk, wv.z, acc[c + 2]);
        acc[c + 3] = fmaf(xk, wv.w, acc[c + 3]);
      }
    }
  }

  if (gr < n) {
    float d = dinv[gr];
    unsigned int* yr = Ybf + (size_t)gr * (NCOL / 2) + cgrp * 8;
    uint4 o0, o1;
    o0.x = bf16pair(acc[0] * d,  acc[1] * d);
    o0.y = bf16pair(acc[2] * d,  acc[3] * d);
    o0.z = bf16pair(acc[4] * d,  acc[5] * d);
    o0.w = bf16pair(acc[6] * d,  acc[7] * d);
    o1.x = bf16pair(acc[8] * d,  acc[9] * d);
    o1.y = bf16pair(acc[10] * d, acc[11] * d);
    o1.z = bf16pair(acc[12] * d, acc[13] * d);
    o1.w = bf16pair(acc[14] * d, acc[15] * d);
    *reinterpret_cast<uint4*>(yr) = o0;
    *reinterpret_cast<uint4*>(yr + 4) = o1;
  }
}

// ---------------- CSR gather-aggregate over bf16 messages ----------------
// Wave per dst node. 8 groups x 8 lanes: group g handles edges p+g, lane l
// loads uint4 (cols 8l..8l+8) -> 8 independent 128B gathers in flight/iter.

template<bool RELU>
__global__ __launch_bounds__(256) void aggregate(
    const int* __restrict__ rowptr, const int* __restrict__ csr_src,
    const uint4* __restrict__ Ybf4, const float* __restrict__ dinv,
    const float* __restrict__ bias, float* __restrict__ H, int n) {
  int nd = (blockIdx.x * blockDim.x + threadIdx.x) >> 6;
  if (nd >= n) return;
  nd = __builtin_amdgcn_readfirstlane(nd);
  int lane = threadIdx.x & 63;
  int l = lane & 7;        // uint4 slot within row (cols 8l..8l+8)
  int g = lane >> 3;       // edge subgroup 0..7
  int lo = rowptr[nd], hi = rowptr[nd + 1];

  float a0 = 0.f, a1 = 0.f, a2 = 0.f, a3 = 0.f,
        a4 = 0.f, a5 = 0.f, a6 = 0.f, a7 = 0.f;

  for (int p = lo + g; p < hi; p += 8) {
    int s = csr_src[p];
    uint4 v = Ybf4[(size_t)s * 8 + l];
    a0 += bf_lo(v.x); a1 += bf_hi(v.x);
    a2 += bf_lo(v.y); a3 += bf_hi(v.y);
    a4 += bf_lo(v.z); a5 += bf_hi(v.z);
    a6 += bf_lo(v.w); a7 += bf_hi(v.w);
  }

#pragma unroll
  for (int m = 8; m < 64; m <<= 1) {
    a0 += __shfl_xor(a0, m); a1 += __shfl_xor(a1, m);
    a2 += __shfl_xor(a2, m); a3 += __shfl_xor(a3, m);
    a4 += __shfl_xor(a4, m); a5 += __shfl_xor(a5, m);
    a6 += __shfl_xor(a6, m); a7 += __shfl_xor(a7, m);
  }

  if (g == 0) {
    uint4 v = Ybf4[(size_t)nd * 8 + l];   // self-loop term
    a0 += bf_lo(v.x); a1 += bf_hi(v.x);
    a2 += bf_lo(v.y); a3 += bf_hi(v.y);
    a4 += bf_lo(v.z); a5 += bf_hi(v.z);
    a6 += bf_lo(v.w); a7 += bf_hi(v.w);
    float d = dinv[nd];
    float4 b0 = *reinterpret_cast<const float4*>(bias + l * 8);
    float4 b1 = *reinterpret_cast<const float4*>(bias + l * 8 + 4);
    float4 o0, o1;
    o0.x = fmaf(d, a0, b0.x); o0.y = fmaf(d, a1, b0.y);
    o0.z = fmaf(d, a2, b0.z); o0.w = fmaf(d, a3, b0.w);
    o1.x = fmaf(d, a4, b1.x); o1.y = fmaf(d, a5, b1.y);
    o1.z = fmaf(d, a6, b1.z); o1.w = fmaf(d, a7, b1.w);
    if (RELU) {
      o0.x = fmaxf(o0.x, 0.f); o0.y = fmaxf(o0.y, 0.f);
      o0.z = fmaxf(o0.z, 0.f); o0.w = fmaxf(o0.w, 0.f);
      o1.x = fmaxf(o1.x, 0.f); o1.y = fmaxf(o1.y, 0.f);
      o1.z = fmaxf(o1.z, 0.f); o1.w = fmaxf(o1.w, 0.f);
    }
    float* hr = H + (size_t)nd * NCOL + l * 8;
    *reinterpret_cast<float4*>(hr) = o0;
    *reinterpret_cast<float4*>(hr + 4) = o1;
  }
}

// ---------------- pooling: pool[g,:] += H over sorted batch runs ----------------

#define NPG 64

__global__ void pool_kernel(const float* __restrict__ H, const int* __restrict__ batch,
                            float* __restrict__ pool, int n) {
  int gid = (blockIdx.x * blockDim.x + threadIdx.x) >> 6;
  int c = threadIdx.x & 63;
  int n0 = gid * NPG;
  if (n0 >= n) return;
  int n1 = min(n0 + NPG, n);
  float acc = 0.f;
  int curg = batch[n0];
  for (int nd = n0; nd < n1; ++nd) {
    int g = batch[nd];
    if (g != curg) {
      atomicAdd(&pool[(size_t)curg * NCOL + c], acc);
      acc = 0.f;
      curg = g;
    }
    acc += H[(size_t)nd * NCOL + c];
  }
  atomicAdd(&pool[(size_t)curg * NCOL + c], acc);
}

// ---------------- final tiny GEMM: out = (pool/cnt) @ Wl + bl ----------------

__global__ void final_kernel(const float* __restrict__ pool, const int* __restrict__ startg,
                             const int* __restrict__ endg, const float* __restrict__ Wl,
                             const float* __restrict__ bl, float* __restrict__ out, int ng) {
  int t = threadIdx.x;
  if (t >= ng * 6) return;
  int g = t / 6, o = t % 6;
  float cntf = (float)(endg[g] - startg[g]);
  float inv = 1.0f / fmaxf(cntf, 1.0f);
  float s = 0.f;
#pragma unroll
  for (int c = 0; c < NCOL; ++c) s += pool[(size_t)g * NCOL + c] * Wl[c * 6 + o];
  out[t] = fmaf(s, inv, bl[o]);
}

// ---------------- launch ----------------

extern "C" void kernel_launch(void* const* d_in, const int* in_sizes, int n_in,
                              void* d_out, int out_size, void* d_ws, size_t ws_size,
                              hipStream_t stream) {
  const float* x    = (const float*)d_in[0];
  const int*   ei   = (const int*)d_in[1];
  const int*   batch= (const int*)d_in[2];
  const float* W1   = (const float*)d_in[3];
  const float* b1   = (const float*)d_in[4];
  const float* W2   = (const float*)d_in[5];
  const float* b2   = (const float*)d_in[6];
  const float* Wl   = (const float*)d_in[7];
  const float* bl   = (const float*)d_in[8];
  float* out = (float*)d_out;

  int n  = in_sizes[0] / 128;   // 100000
  int ne = in_sizes[1] / 2;     // 1600000
  int ng = out_size / 6;        // 64
  const int* srcI = ei;
  const int* dstI = ei + ne;

  int nb   = (n + 255) >> BSH;            // 391 buckets
  int nblk = (ne + EPB - 1) / EPB;        // 782 P1 blocks

  char* w = (char*)d_ws;
  size_t o = 0;
  auto take = [&](size_t bytes) -> char* {
    char* p = w + o;
    o = (o + bytes + 255) & ~(size_t)255;
    return p;
  };
  float*        dinv    = (float*)take((size_t)n * 4);
  int*          degi    = (int*)  take((size_t)n * 4);
  int*          rowptr  = (int*)  take((size_t)(n + 1) * 4);
  int*          csr_src = (int*)  take((size_t)ne * 4);
  unsigned int* ent     = (unsigned int*)take((size_t)ne * 4);
  int*          blockOff= (int*)  take((size_t)nblk * nb * 4);
  unsigned int* Ybf     = (unsigned int*)take((size_t)n * (NCOL / 2) * 4);
  float*        H       = (float*)take((size_t)n * NCOL * 4);
  float*        pool    = (float*)take(4096 * 4);
  int*          startg  = (int*)  take(64 * 4);
  int*          endg    = (int*)  take(64 * 4);
  int*          tsum    = (int*)  take(16384 * 4);
  int*          toff    = (int*)  take(16384 * 4);

  hipMemsetAsync(pool, 0, 4096 * 4, stream);
  hipMemsetAsync(startg, 0, 64 * 4, stream);
  hipMemsetAsync(endg, 0, 64 * 4, stream);

  int nb256 = (n + 255) / 256;
  int nthreads = (n + SCAN_C - 1) / SCAN_C;
  int nbScan = (nthreads + 255) / 256;

  // CSR build via two-phase LDS binning (all global writes coalesced)
  bin_p1<<<nblk, 256, 0, stream>>>(srcI, dstI, ent, blockOff, ne, nb);
  deg_bin<<<nb, 256, 0, stream>>>(ent, blockOff, degi, n, ne, nb, nblk);
  bounds_kernel<<<nb256, 256, 0, stream>>>(batch, startg, endg, n);
  dinv_kernel<<<nb256, 256, 0, stream>>>(degi, dinv, n);
  scan_part<<<nbScan, 256, 0, stream>>>(degi, tsum, n, nthreads);
  scan_mid<<<1, 1024, 0, stream>>>(tsum, toff, nthreads);
  scan_fill<<<nbScan, 256, 0, stream>>>(degi, toff, rowptr, n, nthreads);
  bin_p2<<<nb, 256, 0, stream>>>(ent, blockOff, rowptr, csr_src, n, ne, nb, nblk);

  int nbAgg = (n * 64 + 255) / 256;
  int nbGemm = (n + 63) / 64;

  // layer 1: Ybf = bf16((x@W1)*dinv) ; H = relu(dinv*(Y_self + sum Y[src]) + b1)
  gemm_tiled<128><<<nbGemm, 256, 0, stream>>>(x, W1, dinv, Ybf, n);
  aggregate<true><<<nbAgg, 256, 0, stream>>>(rowptr, csr_src, (const uint4*)Ybf, dinv, b1, H, n);

  // layer 2: Ybf = bf16((H@W2)*dinv) ; H = dinv*(Y_self + sum Y[src]) + b2
  gemm_tiled<64><<<nbGemm, 256, 0, stream>>>(H, W2, dinv, Ybf, n);
  aggregate<false><<<nbAgg, 256, 0, stream>>>(rowptr, csr_src, (const uint4*)Ybf, dinv, b2, H, n);

  // pool + head
  int ngroups = (n + NPG - 1) / NPG;
  int pblocks = (ngroups * 64 + 255) / 256;
  pool_kernel<<<pblocks, 256, 0, stream>>>(H, batch, pool, n);
  final_kernel<<<1, 384, 0, stream>>>(pool, startg, endg, Wl, bl, out, ng);
}

// Round 14
// 248.304 us; speedup vs baseline: 1.7226x; 1.0347x over previous
//
#include <hip/hip_runtime.h>

#define NCOL 64
#define BSH 8                 // 256 dst nodes per bucket
#define NBMAX 512             // padded bucket count (scan width)
#define EPB 2048              // edges per P1 block
#define P2CAP 6144            // LDS out-stage entries (bucket avg 4096, +32 sigma)

// ---------------- bf16 helpers (RNE pack, bit-shift unpack) ----------------

__device__ __forceinline__ unsigned int bf16pair(float a, float b) {
  unsigned int ua = __float_as_uint(a), ub = __float_as_uint(b);
  ua = (ua + 0x7FFFu + ((ua >> 16) & 1u)) >> 16;
  ub = (ub + 0x7FFFu + ((ub >> 16) & 1u)) >> 16;
  return (ub << 16) | ua;
}
__device__ __forceinline__ float bf_lo(unsigned int v) { return __uint_as_float(v << 16); }
__device__ __forceinline__ float bf_hi(unsigned int v) { return __uint_as_float(v & 0xFFFF0000u); }

// ---------------- P1: block-local counting sort of edges by dst bucket ----------------
// Entry pack: (dst&255)<<17 | src   (src < 2^17 on this problem: n = 100000)

__global__ __launch_bounds__(256) void bin_p1(const int* __restrict__ src,
                                              const int* __restrict__ dst,
                                              unsigned int* __restrict__ ent,
                                              int* __restrict__ blockOff,
                                              int ne, int nb) {
  __shared__ int hist[NBMAX];
  __shared__ int base[NBMAX];
  __shared__ int part[256];
  __shared__ unsigned int stage[EPB];
  int tid = threadIdx.x;
  int e0 = blockIdx.x * EPB;
  int cnt = min(EPB, ne - e0);

  for (int i = tid; i < NBMAX; i += 256) hist[i] = 0;
  __syncthreads();
  for (int i = tid; i < cnt; i += 256) {
    int d = dst[e0 + i];
    atomicAdd(&hist[d >> BSH], 1);
  }
  __syncthreads();

  int a0 = hist[2 * tid], a1 = hist[2 * tid + 1];
  int s = a0 + a1;
  part[tid] = s;
  __syncthreads();
  for (int d = 1; d < 256; d <<= 1) {
    int v = (tid >= d) ? part[tid - d] : 0;
    __syncthreads();
    part[tid] += v;
    __syncthreads();
  }
  int off = part[tid] - s;
  base[2 * tid] = off;
  base[2 * tid + 1] = off + a0;
  __syncthreads();

  for (int b = tid; b < nb; b += 256) blockOff[(size_t)blockIdx.x * nb + b] = base[b];
  for (int i = tid; i < NBMAX; i += 256) hist[i] = base[i];
  __syncthreads();

  for (int i = tid; i < cnt; i += 256) {
    int d = dst[e0 + i];
    int sv = src[e0 + i];
    unsigned int e = ((unsigned int)(d & ((1 << BSH) - 1)) << 17) | (unsigned int)sv;
    int p = atomicAdd(&hist[d >> BSH], 1);
    stage[p] = e;
  }
  __syncthreads();
  for (int i = tid; i < cnt; i += 256) ent[e0 + i] = stage[i];
}

// ---------------- degree from binned entries (LDS counters, coalesced writes) ----------------

__global__ __launch_bounds__(256) void deg_bin(const unsigned int* __restrict__ ent,
                                               const int* __restrict__ blockOff,
                                               int* __restrict__ degi,
                                               int n, int ne, int nb, int nblk) {
  __shared__ int cnt[256];
  int b = blockIdx.x;
  int tid = threadIdx.x;
  cnt[tid] = 0;
  __syncthreads();
  for (int blk = tid; blk < nblk; blk += 256) {
    int e0 = blk * EPB;
    int bcnt = min(EPB, ne - e0);
    int st = blockOff[(size_t)blk * nb + b];
    int en = (b + 1 < nb) ? blockOff[(size_t)blk * nb + b + 1] : bcnt;
    for (int i = st; i < en; ++i) {
      unsigned int e = ent[e0 + i];
      atomicAdd(&cnt[e >> 17], 1);
    }
  }
  __syncthreads();
  int node = (b << BSH) + tid;
  if (node < n) degi[node] = cnt[tid];
}

__global__ void dinv_kernel(const int* __restrict__ degi, float* __restrict__ dinv, int n) {
  int i = blockIdx.x * blockDim.x + threadIdx.x;
  if (i < n) dinv[i] = rsqrtf((float)degi[i] + 1.0f);
}

// ---------------- graph-run boundaries (batch is SORTED -> no atomics) ----------------

__global__ void bounds_kernel(const int* __restrict__ batch, int* __restrict__ startg,
                              int* __restrict__ endg, int n) {
  int i = blockIdx.x * blockDim.x + threadIdx.x;
  if (i >= n) return;
  int b = batch[i];
  if (i == 0) {
    startg[b] = 0;
  } else {
    int bp = batch[i - 1];
    if (b != bp) { startg[b] = i; endg[bp] = i; }
  }
  if (i == n - 1) endg[b] = n;
}

// ---------------- 3-pass exclusive scan of degrees -> rowptr[0..n] ----------------

#define SCAN_C 8

__global__ void scan_part(const int* __restrict__ degi, int* __restrict__ tsum,
                          int n, int nthreads) {
  int t = blockIdx.x * blockDim.x + threadIdx.x;
  if (t >= nthreads) return;
  int lo = t * SCAN_C, hi = min(lo + SCAN_C, n);
  int s = 0;
  for (int i = lo; i < hi; ++i) s += degi[i];
  tsum[t] = s;
}

__global__ void scan_mid(int* __restrict__ tsum, int* __restrict__ toff, int nthreads) {
  __shared__ int part[1024];
  int t = threadIdx.x;
  int chunk = (nthreads + 1023) >> 10;
  int lo = t * chunk, hi = min(lo + chunk, nthreads);
  int s = 0;
  for (int i = lo; i < hi; ++i) s += tsum[i];
  part[t] = s;
  __syncthreads();
  for (int d = 1; d < 1024; d <<= 1) {
    int v = (t >= d) ? part[t - d] : 0;
    __syncthreads();
    part[t] += v;
    __syncthreads();
  }
  int off = part[t] - s;
  for (int i = lo; i < hi; ++i) { toff[i] = off; off += tsum[i]; }
}

__global__ void scan_fill(const int* __restrict__ degi, const int* __restrict__ toff,
                          int* __restrict__ rowptr, int n, int nthreads) {
  int t = blockIdx.x * blockDim.x + threadIdx.x;
  if (t >= nthreads) return;
  int lo = t * SCAN_C, hi = min(lo + SCAN_C, n);
  int off = toff[t];
  for (int i = lo; i < hi; ++i) {
    rowptr[i] = off;
    off += degi[i];
  }
  if (hi == n) rowptr[n] = off;
}

// ---------------- P2: bucket-local LDS scatter -> node-grouped CSR ----------------

__global__ __launch_bounds__(256) void bin_p2(const unsigned int* __restrict__ ent,
                                              const int* __restrict__ blockOff,
                                              const int* __restrict__ rowptr,
                                              int* __restrict__ csr_src,
                                              int n, int ne, int nb, int nblk) {
  __shared__ int cur[256];
  __shared__ int outS[P2CAP];
  int b = blockIdx.x;
  int tid = threadIdx.x;
  int node0 = b << BSH;
  int node1 = min(node0 + 256, n);
  int bucketBase = rowptr[node0];
  int bucketCnt = rowptr[node1] - bucketBase;
  int node = node0 + tid;
  cur[tid] = (node < node1) ? (rowptr[node] - bucketBase) : 0;
  __syncthreads();
  for (int blk = tid; blk < nblk; blk += 256) {
    int e0 = blk * EPB;
    int bcnt = min(EPB, ne - e0);
    int st = blockOff[(size_t)blk * nb + b];
    int en = (b + 1 < nb) ? blockOff[(size_t)blk * nb + b + 1] : bcnt;
    for (int i = st; i < en; ++i) {
      unsigned int e = ent[e0 + i];
      int dL = e >> 17;
      int sv = (int)(e & 0x1FFFFu);
      int p = atomicAdd(&cur[dL], 1);
      if (p < P2CAP) outS[p] = sv;
      else csr_src[bucketBase + p] = sv;   // rare overflow fallback
    }
  }
  __syncthreads();
  int lim = min(bucketCnt, P2CAP);
  for (int i = tid; i < lim; i += 256) csr_src[bucketBase + i] = outS[i];
}

// ---------------- tiled tall-skinny GEMM -> bf16 messages ----------------

template<int K>
__global__ __launch_bounds__(256, 8) void gemm_tiled(
    const float* __restrict__ X, const float* __restrict__ W,
    const float* __restrict__ dinv, unsigned int* __restrict__ Ybf, int n) {
  __shared__ float XS[64][65];
  int tid = threadIdx.x;
  int rows0 = blockIdx.x * 64;
  int lane = tid & 63;
  int cgrp = __builtin_amdgcn_readfirstlane(tid >> 6);
  int gr = rows0 + lane;

  float acc[16];
#pragma unroll
  for (int c = 0; c < 16; ++c) acc[c] = 0.f;

  for (int ks = 0; ks < K; ks += 64) {
    if (ks) __syncthreads();   // protect restage
    int r0 = tid >> 4;
    int c4 = (tid & 15) * 4;
#pragma unroll
    for (int it = 0; it < 4; ++it) {
      int r = r0 + it * 16;
      int gr2 = min(rows0 + r, n - 1);
      float4 v = *reinterpret_cast<const float4*>(X + (size_t)gr2 * K + ks + c4);
      XS[r][c4 + 0] = v.x; XS[r][c4 + 1] = v.y;
      XS[r][c4 + 2] = v.z; XS[r][c4 + 3] = v.w;
    }
    __syncthreads();

    const float* wbase = W + (size_t)ks * NCOL + cgrp * 16;
#pragma unroll 4
    for (int k = 0; k < 64; ++k) {
      float xk = XS[lane][k];
      const float* wr = wbase + (size_t)k * NCOL;
#pragma unroll
      for (int c = 0; c < 16; c += 4) {
        float4 wv = *reinterpret_cast<const float4*>(wr + c);
        acc[c + 0] = fmaf(xk, wv.x, acc[c + 0]);
        acc[c + 1] = fmaf(xk, wv.y, acc[c + 1]);
        acc[c + 2] = fmaf(xk, wv.z, acc[c + 2]);
        acc[c + 3] = fmaf(xk, wv.w, acc[c + 3]);
      }
    }
  }

  if (gr < n) {
    float d = dinv[gr];
    unsigned int* yr = Ybf + (size_t)gr * (NCOL / 2) + cgrp * 8;
    uint4 o0, o1;
    o0.x = bf16pair(acc[0] * d,  acc[1] * d);
    o0.y = bf16pair(acc[2] * d,  acc[3] * d);
    o0.z = bf16pair(acc[4] * d,  acc[5] * d);
    o0.w = bf16pair(acc[6] * d,  acc[7] * d);
    o1.x = bf16pair(acc[8] * d,  acc[9] * d);
    o1.y = bf16pair(acc[10] * d, acc[11] * d);
    o1.z = bf16pair(acc[12] * d, acc[13] * d);
    o1.w = bf16pair(acc[14] * d, acc[15] * d);
    *reinterpret_cast<uint4*>(yr) = o0;
    *reinterpret_cast<uint4*>(yr + 4) = o1;
  }
}

// ---------------- CSR gather-aggregate over bf16 messages ----------------
// Wave per dst node. 8 groups x 8 lanes; 2x unrolled edge loop -> 16
// independent 128B gathers in flight per wave-iteration. Self-loop gather
// hoisted before the loop and folded into group 0 pre-reduce.

template<bool RELU>
__global__ __launch_bounds__(256) void aggregate(
    const int* __restrict__ rowptr, const int* __restrict__ csr_src,
    const uint4* __restrict__ Ybf4, const float* __restrict__ dinv,
    const float* __restrict__ bias, float* __restrict__ H, int n) {
  int nd = (blockIdx.x * blockDim.x + threadIdx.x) >> 6;
  if (nd >= n) return;
  nd = __builtin_amdgcn_readfirstlane(nd);
  int lane = threadIdx.x & 63;
  int l = lane & 7;        // uint4 slot within row (cols 8l..8l+8)
  int g = lane >> 3;       // edge subgroup 0..7
  int lo = rowptr[nd], hi = rowptr[nd + 1];

  float a0 = 0.f, a1 = 0.f, a2 = 0.f, a3 = 0.f,
        a4 = 0.f, a5 = 0.f, a6 = 0.f, a7 = 0.f;

  // self-loop gather issued early; folded into group 0 before the reduce
  uint4 vs;
  if (g == 0) vs = Ybf4[(size_t)nd * 8 + l];

  int p = lo + g;
  // 2x unrolled: 16 gathers in flight per wave iteration
  for (; p + 8 < hi; p += 16) {
    int s0 = csr_src[p];
    int s1 = csr_src[p + 8];
    uint4 v0 = Ybf4[(size_t)s0 * 8 + l];
    uint4 v1 = Ybf4[(size_t)s1 * 8 + l];
    a0 += bf_lo(v0.x); a1 += bf_hi(v0.x);
    a2 += bf_lo(v0.y); a3 += bf_hi(v0.y);
    a4 += bf_lo(v0.z); a5 += bf_hi(v0.z);
    a6 += bf_lo(v0.w); a7 += bf_hi(v0.w);
    a0 += bf_lo(v1.x); a1 += bf_hi(v1.x);
    a2 += bf_lo(v1.y); a3 += bf_hi(v1.y);
    a4 += bf_lo(v1.z); a5 += bf_hi(v1.z);
    a6 += bf_lo(v1.w); a7 += bf_hi(v1.w);
  }
  if (p < hi) {
    int s = csr_src[p];
    uint4 v = Ybf4[(size_t)s * 8 + l];
    a0 += bf_lo(v.x); a1 += bf_hi(v.x);
    a2 += bf_lo(v.y); a3 += bf_hi(v.y);
    a4 += bf_lo(v.z); a5 += bf_hi(v.z);
    a6 += bf_lo(v.w); a7 += bf_hi(v.w);
  }

  if (g == 0) {  // fold self-loop pre-reduce
    a0 += bf_lo(vs.x); a1 += bf_hi(vs.x);
    a2 += bf_lo(vs.y); a3 += bf_hi(vs.y);
    a4 += bf_lo(vs.z); a5 += bf_hi(vs.z);
    a6 += bf_lo(vs.w); a7 += bf_hi(vs.w);
  }

#pragma unroll
  for (int m = 8; m < 64; m <<= 1) {
    a0 += __shfl_xor(a0, m); a1 += __shfl_xor(a1, m);
    a2 += __shfl_xor(a2, m); a3 += __shfl_xor(a3, m);
    a4 += __shfl_xor(a4, m); a5 += __shfl_xor(a5, m);
    a6 += __shfl_xor(a6, m); a7 += __shfl_xor(a7, m);
  }

  if (g == 0) {
    float d = dinv[nd];
    float4 b0 = *reinterpret_cast<const float4*>(bias + l * 8);
    float4 b1 = *reinterpret_cast<const float4*>(bias + l * 8 + 4);
    float4 o0, o1;
    o0.x = fmaf(d, a0, b0.x); o0.y = fmaf(d, a1, b0.y);
    o0.z = fmaf(d, a2, b0.z); o0.w = fmaf(d, a3, b0.w);
    o1.x = fmaf(d, a4, b1.x); o1.y = fmaf(d, a5, b1.y);
    o1.z = fmaf(d, a6, b1.z); o1.w = fmaf(d, a7, b1.w);
    if (RELU) {
      o0.x = fmaxf(o0.x, 0.f); o0.y = fmaxf(o0.y, 0.f);
      o0.z = fmaxf(o0.z, 0.f); o0.w = fmaxf(o0.w, 0.f);
      o1.x = fmaxf(o1.x, 0.f); o1.y = fmaxf(o1.y, 0.f);
      o1.z = fmaxf(o1.z, 0.f); o1.w = fmaxf(o1.w, 0.f);
    }
    float* hr = H + (size_t)nd * NCOL + l * 8;
    *reinterpret_cast<float4*>(hr) = o0;
    *reinterpret_cast<float4*>(hr + 4) = o1;
  }
}

// ---------------- pooling: pool[g,:] += H over sorted batch runs ----------------

#define NPG 64

__global__ void pool_kernel(const float* __restrict__ H, const int* __restrict__ batch,
                            float* __restrict__ pool, int n) {
  int gid = (blockIdx.x * blockDim.x + threadIdx.x) >> 6;
  int c = threadIdx.x & 63;
  int n0 = gid * NPG;
  if (n0 >= n) return;
  int n1 = min(n0 + NPG, n);
  float acc = 0.f;
  int curg = batch[n0];
  for (int nd = n0; nd < n1; ++nd) {
    int g = batch[nd];
    if (g != curg) {
      atomicAdd(&pool[(size_t)curg * NCOL + c], acc);
      acc = 0.f;
      curg = g;
    }
    acc += H[(size_t)nd * NCOL + c];
  }
  atomicAdd(&pool[(size_t)curg * NCOL + c], acc);
}

// ---------------- final tiny GEMM: out = (pool/cnt) @ Wl + bl ----------------

__global__ void final_kernel(const float* __restrict__ pool, const int* __restrict__ startg,
                             const int* __restrict__ endg, const float* __restrict__ Wl,
                             const float* __restrict__ bl, float* __restrict__ out, int ng) {
  int t = threadIdx.x;
  if (t >= ng * 6) return;
  int g = t / 6, o = t % 6;
  float cntf = (float)(endg[g] - startg[g]);
  float inv = 1.0f / fmaxf(cntf, 1.0f);
  float s = 0.f;
#pragma unroll
  for (int c = 0; c < NCOL; ++c) s += pool[(size_t)g * NCOL + c] * Wl[c * 6 + o];
  out[t] = fmaf(s, inv, bl[o]);
}

// ---------------- launch ----------------

extern "C" void kernel_launch(void* const* d_in, const int* in_sizes, int n_in,
                              void* d_out, int out_size, void* d_ws, size_t ws_size,
                              hipStream_t stream) {
  const float* x    = (const float*)d_in[0];
  const int*   ei   = (const int*)d_in[1];
  const int*   batch= (const int*)d_in[2];
  const float* W1   = (const float*)d_in[3];
  const float* b1   = (const float*)d_in[4];
  const float* W2   = (const float*)d_in[5];
  const float* b2   = (const float*)d_in[6];
  const float* Wl   = (const float*)d_in[7];
  const float* bl   = (const float*)d_in[8];
  float* out = (float*)d_out;

  int n  = in_sizes[0] / 128;   // 100000
  int ne = in_sizes[1] / 2;     // 1600000
  int ng = out_size / 6;        // 64
  const int* srcI = ei;
  const int* dstI = ei + ne;

  int nb   = (n + 255) >> BSH;            // 391 buckets
  int nblk = (ne + EPB - 1) / EPB;        // 782 P1 blocks

  char* w = (char*)d_ws;
  size_t o = 0;
  auto take = [&](size_t bytes) -> char* {
    char* p = w + o;
    o = (o + bytes + 255) & ~(size_t)255;
    return p;
  };
  float*        dinv    = (float*)take((size_t)n * 4);
  int*          degi    = (int*)  take((size_t)n * 4);
  int*          rowptr  = (int*)  take((size_t)(n + 1) * 4);
  int*          csr_src = (int*)  take((size_t)ne * 4);
  unsigned int* ent     = (unsigned int*)take((size_t)ne * 4);
  int*          blockOff= (int*)  take((size_t)nblk * nb * 4);
  unsigned int* Ybf     = (unsigned int*)take((size_t)n * (NCOL / 2) * 4);
  float*        H       = (float*)take((size_t)n * NCOL * 4);
  float*        pool    = (float*)take(4096 * 4);
  int*          startg  = (int*)  take(64 * 4);
  int*          endg    = (int*)  take(64 * 4);
  int*          tsum    = (int*)  take(16384 * 4);
  int*          toff    = (int*)  take(16384 * 4);

  hipMemsetAsync(pool, 0, 4096 * 4, stream);
  hipMemsetAsync(startg, 0, 64 * 4, stream);
  hipMemsetAsync(endg, 0, 64 * 4, stream);

  int nb256 = (n + 255) / 256;
  int nthreads = (n + SCAN_C - 1) / SCAN_C;
  int nbScan = (nthreads + 255) / 256;

  // CSR build via two-phase LDS binning (all global writes coalesced)
  bin_p1<<<nblk, 256, 0, stream>>>(srcI, dstI, ent, blockOff, ne, nb);
  deg_bin<<<nb, 256, 0, stream>>>(ent, blockOff, degi, n, ne, nb, nblk);
  bounds_kernel<<<nb256, 256, 0, stream>>>(batch, startg, endg, n);
  dinv_kernel<<<nb256, 256, 0, stream>>>(degi, dinv, n);
  scan_part<<<nbScan, 256, 0, stream>>>(degi, tsum, n, nthreads);
  scan_mid<<<1, 1024, 0, stream>>>(tsum, toff, nthreads);
  scan_fill<<<nbScan, 256, 0, stream>>>(degi, toff, rowptr, n, nthreads);
  bin_p2<<<nb, 256, 0, stream>>>(ent, blockOff, rowptr, csr_src, n, ne, nb, nblk);

  int nbAgg = (n * 64 + 255) / 256;
  int nbGemm = (n + 63) / 64;

  // layer 1: Ybf = bf16((x@W1)*dinv) ; H = relu(dinv*(Y_self + sum Y[src]) + b1)
  gemm_tiled<128><<<nbGemm, 256, 0, stream>>>(x, W1, dinv, Ybf, n);
  aggregate<true><<<nbAgg, 256, 0, stream>>>(rowptr, csr_src, (const uint4*)Ybf, dinv, b1, H, n);

  // layer 2: Ybf = bf16((H@W2)*dinv) ; H = dinv*(Y_self + sum Y[src]) + b2
  gemm_tiled<64><<<nbGemm, 256, 0, stream>>>(H, W2, dinv, Ybf, n);
  aggregate<false><<<nbAgg, 256, 0, stream>>>(rowptr, csr_src, (const uint4*)Ybf, dinv, b2, H, n);

  // pool + head
  int ngroups = (n + NPG - 1) / NPG;
  int pblocks = (ngroups * 64 + 255) / 256;
  pool_kernel<<<pblocks, 256, 0, stream>>>(H, batch, pool, n);
  final_kernel<<<1, 384, 0, stream>>>(pool, startg, endg, Wl, bl, out, ng);
}

// Round 15
// 237.009 us; speedup vs baseline: 1.8047x; 1.0477x over previous
//
#include <hip/hip_runtime.h>

#define NCOL 64
#define BSH 8                 // 256 dst nodes per bucket
#define NBMAX 512             // padded bucket count (scan width)
#define EPB 2048              // edges per P1 block
#define P2CAP 6144            // LDS out-stage entries (bucket avg 4096, +32 sigma)

// ---------------- bf16 helpers (RNE pack, bit-shift unpack) ----------------

__device__ __forceinline__ unsigned int bf16pair(float a, float b) {
  unsigned int ua = __float_as_uint(a), ub = __float_as_uint(b);
  ua = (ua + 0x7FFFu + ((ua >> 16) & 1u)) >> 16;
  ub = (ub + 0x7FFFu + ((ub >> 16) & 1u)) >> 16;
  return (ub << 16) | ua;
}
__device__ __forceinline__ float bf_lo(unsigned int v) { return __uint_as_float(v << 16); }
__device__ __forceinline__ float bf_hi(unsigned int v) { return __uint_as_float(v & 0xFFFF0000u); }

// ---------------- P1: block-local counting sort of edges by dst bucket ----------------
// Entry pack: (dst&255)<<17 | src   (src < 2^17 on this problem: n = 100000)

__global__ __launch_bounds__(256) void bin_p1(const int* __restrict__ src,
                                              const int* __restrict__ dst,
                                              unsigned int* __restrict__ ent,
                                              int* __restrict__ blockOff,
                                              int ne, int nb) {
  __shared__ int hist[NBMAX];
  __shared__ int base[NBMAX];
  __shared__ int part[256];
  __shared__ unsigned int stage[EPB];
  int tid = threadIdx.x;
  int e0 = blockIdx.x * EPB;
  int cnt = min(EPB, ne - e0);

  for (int i = tid; i < NBMAX; i += 256) hist[i] = 0;
  __syncthreads();
  for (int i = tid; i < cnt; i += 256) {
    int d = dst[e0 + i];
    atomicAdd(&hist[d >> BSH], 1);
  }
  __syncthreads();

  int a0 = hist[2 * tid], a1 = hist[2 * tid + 1];
  int s = a0 + a1;
  part[tid] = s;
  __syncthreads();
  for (int d = 1; d < 256; d <<= 1) {
    int v = (tid >= d) ? part[tid - d] : 0;
    __syncthreads();
    part[tid] += v;
    __syncthreads();
  }
  int off = part[tid] - s;
  base[2 * tid] = off;
  base[2 * tid + 1] = off + a0;
  __syncthreads();

  for (int b = tid; b < nb; b += 256) blockOff[(size_t)blockIdx.x * nb + b] = base[b];
  for (int i = tid; i < NBMAX; i += 256) hist[i] = base[i];
  __syncthreads();

  for (int i = tid; i < cnt; i += 256) {
    int d = dst[e0 + i];
    int sv = src[e0 + i];
    unsigned int e = ((unsigned int)(d & ((1 << BSH) - 1)) << 17) | (unsigned int)sv;
    int p = atomicAdd(&hist[d >> BSH], 1);
    stage[p] = e;
  }
  __syncthreads();
  for (int i = tid; i < cnt; i += 256) ent[e0 + i] = stage[i];
}

// ---------------- degree from binned entries (LDS counters, coalesced writes) ----------------

__global__ __launch_bounds__(256) void deg_bin(const unsigned int* __restrict__ ent,
                                               const int* __restrict__ blockOff,
                                               int* __restrict__ degi,
                                               int n, int ne, int nb, int nblk) {
  __shared__ int cnt[256];
  int b = blockIdx.x;
  int tid = threadIdx.x;
  cnt[tid] = 0;
  __syncthreads();
  for (int blk = tid; blk < nblk; blk += 256) {
    int e0 = blk * EPB;
    int bcnt = min(EPB, ne - e0);
    int st = blockOff[(size_t)blk * nb + b];
    int en = (b + 1 < nb) ? blockOff[(size_t)blk * nb + b + 1] : bcnt;
    for (int i = st; i < en; ++i) {
      unsigned int e = ent[e0 + i];
      atomicAdd(&cnt[e >> 17], 1);
    }
  }
  __syncthreads();
  int node = (b << BSH) + tid;
  if (node < n) degi[node] = cnt[tid];
}

__global__ void dinv_kernel(const int* __restrict__ degi, float* __restrict__ dinv, int n) {
  int i = blockIdx.x * blockDim.x + threadIdx.x;
  if (i < n) dinv[i] = rsqrtf((float)degi[i] + 1.0f);
}

// ---------------- graph-run boundaries (batch is SORTED -> no atomics) ----------------

__global__ void bounds_kernel(const int* __restrict__ batch, int* __restrict__ startg,
                              int* __restrict__ endg, int n) {
  int i = blockIdx.x * blockDim.x + threadIdx.x;
  if (i >= n) return;
  int b = batch[i];
  if (i == 0) {
    startg[b] = 0;
  } else {
    int bp = batch[i - 1];
    if (b != bp) { startg[b] = i; endg[bp] = i; }
  }
  if (i == n - 1) endg[b] = n;
}

// ---------------- 3-pass exclusive scan of degrees -> rowptr[0..n] ----------------

#define SCAN_C 8

__global__ void scan_part(const int* __restrict__ degi, int* __restrict__ tsum,
                          int n, int nthreads) {
  int t = blockIdx.x * blockDim.x + threadIdx.x;
  if (t >= nthreads) return;
  int lo = t * SCAN_C, hi = min(lo + SCAN_C, n);
  int s = 0;
  for (int i = lo; i < hi; ++i) s += degi[i];
  tsum[t] = s;
}

__global__ void scan_mid(int* __restrict__ tsum, int* __restrict__ toff, int nthreads) {
  __shared__ int part[1024];
  int t = threadIdx.x;
  int chunk = (nthreads + 1023) >> 10;
  int lo = t * chunk, hi = min(lo + chunk, nthreads);
  int s = 0;
  for (int i = lo; i < hi; ++i) s += tsum[i];
  part[t] = s;
  __syncthreads();
  for (int d = 1; d < 1024; d <<= 1) {
    int v = (t >= d) ? part[t - d] : 0;
    __syncthreads();
    part[t] += v;
    __syncthreads();
  }
  int off = part[t] - s;
  for (int i = lo; i < hi; ++i) { toff[i] = off; off += tsum[i]; }
}

__global__ void scan_fill(const int* __restrict__ degi, const int* __restrict__ toff,
                          int* __restrict__ rowptr, int n, int nthreads) {
  int t = blockIdx.x * blockDim.x + threadIdx.x;
  if (t >= nthreads) return;
  int lo = t * SCAN_C, hi = min(lo + SCAN_C, n);
  int off = toff[t];
  for (int i = lo; i < hi; ++i) {
    rowptr[i] = off;
    off += degi[i];
  }
  if (hi == n) rowptr[n] = off;
}

// ---------------- P2: bucket-local LDS scatter -> node-grouped CSR ----------------

__global__ __launch_bounds__(256) void bin_p2(const unsigned int* __restrict__ ent,
                                              const int* __restrict__ blockOff,
                                              const int* __restrict__ rowptr,
                                              int* __restrict__ csr_src,
                                              int n, int ne, int nb, int nblk) {
  __shared__ int cur[256];
  __shared__ int outS[P2CAP];
  int b = blockIdx.x;
  int tid = threadIdx.x;
  int node0 = b << BSH;
  int node1 = min(node0 + 256, n);
  int bucketBase = rowptr[node0];
  int bucketCnt = rowptr[node1] - bucketBase;
  int node = node0 + tid;
  cur[tid] = (node < node1) ? (rowptr[node] - bucketBase) : 0;
  __syncthreads();
  for (int blk = tid; blk < nblk; blk += 256) {
    int e0 = blk * EPB;
    int bcnt = min(EPB, ne - e0);
    int st = blockOff[(size_t)blk * nb + b];
    int en = (b + 1 < nb) ? blockOff[(size_t)blk * nb + b + 1] : bcnt;
    for (int i = st; i < en; ++i) {
      unsigned int e = ent[e0 + i];
      int dL = e >> 17;
      int sv = (int)(e & 0x1FFFFu);
      int p = atomicAdd(&cur[dL], 1);
      if (p < P2CAP) outS[p] = sv;
      else csr_src[bucketBase + p] = sv;   // rare overflow fallback
    }
  }
  __syncthreads();
  int lim = min(bucketCnt, P2CAP);
  for (int i = tid; i < lim; i += 256) csr_src[bucketBase + i] = outS[i];
}

// ---------------- tiled tall-skinny GEMM -> bf16 messages ----------------

template<int K>
__global__ __launch_bounds__(256, 8) void gemm_tiled(
    const float* __restrict__ X, const float* __restrict__ W,
    const float* __restrict__ dinv, unsigned int* __restrict__ Ybf, int n) {
  __shared__ float XS[64][65];
  int tid = threadIdx.x;
  int rows0 = blockIdx.x * 64;
  int lane = tid & 63;
  int cgrp = __builtin_amdgcn_readfirstlane(tid >> 6);
  int gr = rows0 + lane;

  float acc[16];
#pragma unroll
  for (int c = 0; c < 16; ++c) acc[c] = 0.f;

  for (int ks = 0; ks < K; ks += 64) {
    if (ks) __syncthreads();   // protect restage
    int r0 = tid >> 4;
    int c4 = (tid & 15) * 4;
#pragma unroll
    for (int it = 0; it < 4; ++it) {
      int r = r0 + it * 16;
      int gr2 = min(rows0 + r, n - 1);
      float4 v = *reinterpret_cast<const float4*>(X + (size_t)gr2 * K + ks + c4);
      XS[r][c4 + 0] = v.x; XS[r][c4 + 1] = v.y;
      XS[r][c4 + 2] = v.z; XS[r][c4 + 3] = v.w;
    }
    __syncthreads();

    const float* wbase = W + (size_t)ks * NCOL + cgrp * 16;
#pragma unroll 4
    for (int k = 0; k < 64; ++k) {
      float xk = XS[lane][k];
      const float* wr = wbase + (size_t)k * NCOL;
#pragma unroll
      for (int c = 0; c < 16; c += 4) {
        float4 wv = *reinterpret_cast<const float4*>(wr + c);
        acc[c + 0] = fmaf(xk, wv.x, acc[c + 0]);
        acc[c + 1] = fmaf(xk, wv.y, acc[c + 1]);
        acc[c + 2] = fmaf(xk, wv.z, acc[c + 2]);
        acc[c + 3] = fmaf(xk, wv.w, acc[c + 3]);
      }
    }
  }

  if (gr < n) {
    float d = dinv[gr];
    unsigned int* yr = Ybf + (size_t)gr * (NCOL / 2) + cgrp * 8;
    uint4 o0, o1;
    o0.x = bf16pair(acc[0] * d,  acc[1] * d);
    o0.y = bf16pair(acc[2] * d,  acc[3] * d);
    o0.z = bf16pair(acc[4] * d,  acc[5] * d);
    o0.w = bf16pair(acc[6] * d,  acc[7] * d);
    o1.x = bf16pair(acc[8] * d,  acc[9] * d);
    o1.y = bf16pair(acc[10] * d, acc[11] * d);
    o1.z = bf16pair(acc[12] * d, acc[13] * d);
    o1.w = bf16pair(acc[14] * d, acc[15] * d);
    *reinterpret_cast<uint4*>(yr) = o0;
    *reinterpret_cast<uint4*>(yr + 4) = o1;
  }
}

// ---------------- CSR gather-aggregate over bf16 messages ----------------
// 8-lane GROUP per dst node (wave = 8 nodes): lane l covers cols 8l..8l+8,
// so accumulation is lane-local -- NO cross-lane reduce, no idle finalize.
// Accumulators init from the self-loop row. 2x unroll -> 16 gathers in
// flight per wave. A wave writes 8 consecutive H rows (coalesced).

template<bool RELU>
__global__ __launch_bounds__(256) void aggregate(
    const int* __restrict__ rowptr, const int* __restrict__ csr_src,
    const uint4* __restrict__ Ybf4, const float* __restrict__ dinv,
    const float* __restrict__ bias, float* __restrict__ H, int n) {
  int nd = (blockIdx.x * blockDim.x + threadIdx.x) >> 3;
  if (nd >= n) return;
  int l = threadIdx.x & 7;    // uint4 slot within row (cols 8l..8l+8)
  int lo = rowptr[nd], hi = rowptr[nd + 1];

  // init accumulators from self-loop row
  uint4 vs = Ybf4[(size_t)nd * 8 + l];
  float a0 = bf_lo(vs.x), a1 = bf_hi(vs.x);
  float a2 = bf_lo(vs.y), a3 = bf_hi(vs.y);
  float a4 = bf_lo(vs.z), a5 = bf_hi(vs.z);
  float a6 = bf_lo(vs.w), a7 = bf_hi(vs.w);

  int p = lo;
  for (; p + 1 < hi; p += 2) {   // 2 edges in flight per group
    int s0 = csr_src[p];
    int s1 = csr_src[p + 1];
    uint4 v0 = Ybf4[(size_t)s0 * 8 + l];
    uint4 v1 = Ybf4[(size_t)s1 * 8 + l];
    a0 += bf_lo(v0.x); a1 += bf_hi(v0.x);
    a2 += bf_lo(v0.y); a3 += bf_hi(v0.y);
    a4 += bf_lo(v0.z); a5 += bf_hi(v0.z);
    a6 += bf_lo(v0.w); a7 += bf_hi(v0.w);
    a0 += bf_lo(v1.x); a1 += bf_hi(v1.x);
    a2 += bf_lo(v1.y); a3 += bf_hi(v1.y);
    a4 += bf_lo(v1.z); a5 += bf_hi(v1.z);
    a6 += bf_lo(v1.w); a7 += bf_hi(v1.w);
  }
  if (p < hi) {
    int s = csr_src[p];
    uint4 v = Ybf4[(size_t)s * 8 + l];
    a0 += bf_lo(v.x); a1 += bf_hi(v.x);
    a2 += bf_lo(v.y); a3 += bf_hi(v.y);
    a4 += bf_lo(v.z); a5 += bf_hi(v.z);
    a6 += bf_lo(v.w); a7 += bf_hi(v.w);
  }

  float d = dinv[nd];
  float4 b0 = *reinterpret_cast<const float4*>(bias + l * 8);
  float4 b1 = *reinterpret_cast<const float4*>(bias + l * 8 + 4);
  float4 o0, o1;
  o0.x = fmaf(d, a0, b0.x); o0.y = fmaf(d, a1, b0.y);
  o0.z = fmaf(d, a2, b0.z); o0.w = fmaf(d, a3, b0.w);
  o1.x = fmaf(d, a4, b1.x); o1.y = fmaf(d, a5, b1.y);
  o1.z = fmaf(d, a6, b1.z); o1.w = fmaf(d, a7, b1.w);
  if (RELU) {
    o0.x = fmaxf(o0.x, 0.f); o0.y = fmaxf(o0.y, 0.f);
    o0.z = fmaxf(o0.z, 0.f); o0.w = fmaxf(o0.w, 0.f);
    o1.x = fmaxf(o1.x, 0.f); o1.y = fmaxf(o1.y, 0.f);
    o1.z = fmaxf(o1.z, 0.f); o1.w = fmaxf(o1.w, 0.f);
  }
  float* hr = H + (size_t)nd * NCOL + l * 8;
  *reinterpret_cast<float4*>(hr) = o0;
  *reinterpret_cast<float4*>(hr + 4) = o1;
}

// ---------------- pooling: pool[g,:] += H over sorted batch runs ----------------

#define NPG 64

__global__ void pool_kernel(const float* __restrict__ H, const int* __restrict__ batch,
                            float* __restrict__ pool, int n) {
  int gid = (blockIdx.x * blockDim.x + threadIdx.x) >> 6;
  int c = threadIdx.x & 63;
  int n0 = gid * NPG;
  if (n0 >= n) return;
  int n1 = min(n0 + NPG, n);
  float acc = 0.f;
  int curg = batch[n0];
  for (int nd = n0; nd < n1; ++nd) {
    int g = batch[nd];
    if (g != curg) {
      atomicAdd(&pool[(size_t)curg * NCOL + c], acc);
      acc = 0.f;
      curg = g;
    }
    acc += H[(size_t)nd * NCOL + c];
  }
  atomicAdd(&pool[(size_t)curg * NCOL + c], acc);
}

// ---------------- final tiny GEMM: out = (pool/cnt) @ Wl + bl ----------------

__global__ void final_kernel(const float* __restrict__ pool, const int* __restrict__ startg,
                             const int* __restrict__ endg, const float* __restrict__ Wl,
                             const float* __restrict__ bl, float* __restrict__ out, int ng) {
  int t = threadIdx.x;
  if (t >= ng * 6) return;
  int g = t / 6, o = t % 6;
  float cntf = (float)(endg[g] - startg[g]);
  float inv = 1.0f / fmaxf(cntf, 1.0f);
  float s = 0.f;
#pragma unroll
  for (int c = 0; c < NCOL; ++c) s += pool[(size_t)g * NCOL + c] * Wl[c * 6 + o];
  out[t] = fmaf(s, inv, bl[o]);
}

// ---------------- launch ----------------

extern "C" void kernel_launch(void* const* d_in, const int* in_sizes, int n_in,
                              void* d_out, int out_size, void* d_ws, size_t ws_size,
                              hipStream_t stream) {
  const float* x    = (const float*)d_in[0];
  const int*   ei   = (const int*)d_in[1];
  const int*   batch= (const int*)d_in[2];
  const float* W1   = (const float*)d_in[3];
  const float* b1   = (const float*)d_in[4];
  const float* W2   = (const float*)d_in[5];
  const float* b2   = (const float*)d_in[6];
  const float* Wl   = (const float*)d_in[7];
  const float* bl   = (const float*)d_in[8];
  float* out = (float*)d_out;

  int n  = in_sizes[0] / 128;   // 100000
  int ne = in_sizes[1] / 2;     // 1600000
  int ng = out_size / 6;        // 64
  const int* srcI = ei;
  const int* dstI = ei + ne;

  int nb   = (n + 255) >> BSH;            // 391 buckets
  int nblk = (ne + EPB - 1) / EPB;        // 782 P1 blocks

  char* w = (char*)d_ws;
  size_t o = 0;
  auto take = [&](size_t bytes) -> char* {
    char* p = w + o;
    o = (o + bytes + 255) & ~(size_t)255;
    return p;
  };
  float*        dinv    = (float*)take((size_t)n * 4);
  int*          degi    = (int*)  take((size_t)n * 4);
  int*          rowptr  = (int*)  take((size_t)(n + 1) * 4);
  int*          csr_src = (int*)  take((size_t)ne * 4);
  unsigned int* ent     = (unsigned int*)take((size_t)ne * 4);
  int*          blockOff= (int*)  take((size_t)nblk * nb * 4);
  unsigned int* Ybf     = (unsigned int*)take((size_t)n * (NCOL / 2) * 4);
  float*        H       = (float*)take((size_t)n * NCOL * 4);
  float*        pool    = (float*)take(4096 * 4);
  int*          startg  = (int*)  take(64 * 4);
  int*          endg    = (int*)  take(64 * 4);
  int*          tsum    = (int*)  take(16384 * 4);
  int*          toff    = (int*)  take(16384 * 4);

  hipMemsetAsync(pool, 0, 4096 * 4, stream);
  hipMemsetAsync(startg, 0, 64 * 4, stream);
  hipMemsetAsync(endg, 0, 64 * 4, stream);

  int nb256 = (n + 255) / 256;
  int nthreads = (n + SCAN_C - 1) / SCAN_C;
  int nbScan = (nthreads + 255) / 256;

  // CSR build via two-phase LDS binning (all global writes coalesced)
  bin_p1<<<nblk, 256, 0, stream>>>(srcI, dstI, ent, blockOff, ne, nb);
  deg_bin<<<nb, 256, 0, stream>>>(ent, blockOff, degi, n, ne, nb, nblk);
  bounds_kernel<<<nb256, 256, 0, stream>>>(batch, startg, endg, n);
  dinv_kernel<<<nb256, 256, 0, stream>>>(degi, dinv, n);
  scan_part<<<nbScan, 256, 0, stream>>>(degi, tsum, n, nthreads);
  scan_mid<<<1, 1024, 0, stream>>>(tsum, toff, nthreads);
  scan_fill<<<nbScan, 256, 0, stream>>>(degi, toff, rowptr, n, nthreads);
  bin_p2<<<nb, 256, 0, stream>>>(ent, blockOff, rowptr, csr_src, n, ne, nb, nblk);

  int nbAgg = (n * 8 + 255) / 256;   // 8 lanes per node
  int nbGemm = (n + 63) / 64;

  // layer 1: Ybf = bf16((x@W1)*dinv) ; H = relu(dinv*(Y_self + sum Y[src]) + b1)
  gemm_tiled<128><<<nbGemm, 256, 0, stream>>>(x, W1, dinv, Ybf, n);
  aggregate<true><<<nbAgg, 256, 0, stream>>>(rowptr, csr_src, (const uint4*)Ybf, dinv, b1, H, n);

  // layer 2: Ybf = bf16((H@W2)*dinv) ; H = dinv*(Y_self + sum Y[src]) + b2
  gemm_tiled<64><<<nbGemm, 256, 0, stream>>>(H, W2, dinv, Ybf, n);
  aggregate<false><<<nbAgg, 256, 0, stream>>>(rowptr, csr_src, (const uint4*)Ybf, dinv, b2, H, n);

  // pool + head
  int ngroups = (n + NPG - 1) / NPG;
  int pblocks = (ngroups * 64 + 255) / 256;
  pool_kernel<<<pblocks, 256, 0, stream>>>(H, batch, pool, n);
  final_kernel<<<1, 384, 0, stream>>>(pool, startg, endg, Wl, bl, out, ng);
}